// Round 8
// baseline (197.829 us; speedup 1.0000x reference)
//
#include <hip/hip_runtime.h>

// ---------------------------------------------------------------------------
// MultiHeadAttention: B=2, S=2048, E=1024, H=16, D=64
//   1. prep_kernel (fused): cast x->bf16; transpose+cast w_in, w_out
//      (float4 loads, ushort2 stores).
//   2. GEMM1: qkv[4096,3072] = x @ w_in + b_in (bf16; Q cols pre-scaled by
//      0.125*log2e); V-transpose fused into epilogue (R14).
//      R17: 3-buffer prefetch-distance-2 pipeline with counted s_waitcnt
//      vmcnt(N) + raw s_barrier (T3/T4) — loads age TWO compute phases
//      before their wait instead of being drained fresh by __syncthreads.
//   3. flash attention — 32x32x16 MFMA, wave-pair key-split, dbuf K/V,
//      setprio, hoisted zero C-operand (R10-R13, all HW-verified).
//   4. GEMM2: out = attn @ w_out + b_out. 128x128 tile, 512 thr.
//      R17: same 3-buffer counted-vmcnt pipeline.
// ---------------------------------------------------------------------------

typedef __bf16 bf16x8 __attribute__((ext_vector_type(8)));
typedef float  f32x4  __attribute__((ext_vector_type(4)));
typedef float  f32x16 __attribute__((ext_vector_type(16)));
typedef short  s16x8  __attribute__((ext_vector_type(8)));

__device__ __forceinline__ unsigned short f2b(float f) {
  unsigned u = __float_as_uint(f);
  unsigned r = u + 0x7fffu + ((u >> 16) & 1u);   // round-to-nearest-even
  return (unsigned short)(r >> 16);
}

// gfx950 HW packed fp32->bf16 convert (RNE): low16=cvt(a), high16=cvt(b).
__device__ __forceinline__ unsigned cvt_pk_bf16(float a, float b) {
#if defined(__HIP_DEVICE_COMPILE__)
  unsigned r;
  asm("v_cvt_pk_bf16_f32 %0, %1, %2" : "=v"(r) : "v"(a), "v"(b));
  return r;
#else
  return (unsigned)f2b(a) | ((unsigned)f2b(b) << 16);
#endif
}

// v_permlane32_swap_b32 a, b:  a' = {a_lo, b_lo}, b' = {a_hi, b_hi}
__device__ __forceinline__ void permlane32_swap(unsigned& a, unsigned& b) {
#if defined(__HIP_DEVICE_COMPILE__)
  asm("v_permlane32_swap_b32 %0, %1" : "+v"(a), "+v"(b));
#endif
}

// async global->LDS, 16 bytes per lane; HW writes lane i at lds + i*16.
__device__ __forceinline__ void gl_lds16(const void* g, void* l) {
  __builtin_amdgcn_global_load_lds(
      (__attribute__((address_space(1))) void*)g,
      (__attribute__((address_space(3))) void*)l, 16, 0, 0);
}

#define VMCNT(n) asm volatile("s_waitcnt vmcnt(" #n ")" ::: "memory")

// ---------------------------------------------------------------------------
// prep_kernel: fused elementwise cast (x->xb) + two transpose_cast jobs.
// grid 5120 x 256: [0,4096) cast; [4096,4864) w_in T; [4864,5120) w_out T.
// ---------------------------------------------------------------------------
__device__ __forceinline__ void transpose_cast_body(
    const float* __restrict__ in, unsigned short* __restrict__ out,
    int R, int C, int bx, int by, int tid, float tile[64][65]) {
  int r0 = by * 64, c0 = bx * 64;
#pragma unroll
  for (int p = 0; p < 4; p++) {
    int i = tid + p * 256;              // 0..1023: 64 rows x 16 float4
    int ri = i >> 4, c4 = (i & 15) * 4;
    float4 v = *(const float4*)&in[(size_t)(r0 + ri) * C + c0 + c4];
    tile[ri][c4 + 0] = v.x; tile[ri][c4 + 1] = v.y;
    tile[ri][c4 + 2] = v.z; tile[ri][c4 + 3] = v.w;
  }
  __syncthreads();
#pragma unroll
  for (int p = 0; p < 8; p++) {
    int i = tid + p * 256;              // 0..2047: 64 cols x 32 row-pairs
    int ci = i >> 5, rp = (i & 31) * 2;
    ushort2 o;
    o.x = f2b(tile[rp][ci]);
    o.y = f2b(tile[rp + 1][ci]);
    *(ushort2*)&out[(size_t)(c0 + ci) * R + r0 + rp] = o;
  }
}

__global__ __launch_bounds__(256) void prep_kernel(
    const float* __restrict__ x, unsigned short* __restrict__ xb,
    const float* __restrict__ w_in, unsigned short* __restrict__ wint,
    const float* __restrict__ w_out, unsigned short* __restrict__ woutt) {
  __shared__ float tile[64][65];
  int bid = blockIdx.x, tid = threadIdx.x;
  if (bid < 4096) {
    int i = bid * 256 + tid;   // n4 = 1048576 exactly = 4096*256
    float4 v = ((const float4*)x)[i];
    ushort4 o;
    o.x = f2b(v.x); o.y = f2b(v.y); o.z = f2b(v.z); o.w = f2b(v.w);
    ((ushort4*)xb)[i] = o;
  } else if (bid < 4864) {
    int l = bid - 4096;        // 768 blocks: (48 x, 16 y)
    transpose_cast_body(w_in, wint, 1024, 3072, l % 48, l / 48, tid, tile);
  } else {
    int l = bid - 4864;        // 256 blocks: (16 x, 16 y)
    transpose_cast_body(w_out, woutt, 1024, 1024, l % 16, l / 16, tid, tile);
  }
}

// ---------------------------------------------------------------------------
// GEMM1: C[M,N] = A[M,K]*Bt[N,K]^T + bias[N], bf16 out. 128x128 tile, BK=32.
// R17: 3-buffer distance-2 pipeline, counted vmcnt + raw barriers.
// Blocks with bx>=16 (V cols) also scatter to vt[((b*16+h)*64+d)*2048+s].
// ---------------------------------------------------------------------------
__global__ __launch_bounds__(256) void gemm_bt1(
    const unsigned short* __restrict__ A, const unsigned short* __restrict__ Bt,
    const float* __restrict__ bias, unsigned short* __restrict__ Cp,
    unsigned short* __restrict__ vtp,
    int M, int N, int K, int qcols, float qscale) {
  __shared__ __align__(16) unsigned short As[3][128 * 32];   // 3 x 8KB
  __shared__ __align__(16) unsigned short Bs[3][128 * 32];   // 3 x 8KB
  int tid = threadIdx.x;
  int wave = tid >> 6, lane = tid & 63;
  int m_l = lane & 15, quad = lane >> 4;
  int wm = (wave >> 1) * 64, wn = (wave & 1) * 64;
  int row = tid >> 2, kp = (tid & 3) << 3;
  const unsigned short* ag = A + (size_t)(blockIdx.y * 128 + row) * K + kp;
  const unsigned short* bg = Bt + (size_t)(blockIdx.x * 128 + row) * K + kp;
  f32x4 acc[4][4] = {};

  auto stage = [&](int k0, int s) {     // 4 loads/wave -> vmcnt +4
    gl_lds16(ag + k0, &As[s][wave * 512]);
    gl_lds16(ag + (size_t)64 * K + k0, &As[s][2048 + wave * 512]);
    gl_lds16(bg + k0, &Bs[s][wave * 512]);
    gl_lds16(bg + (size_t)64 * K + k0, &Bs[s][2048 + wave * 512]);
  };
  auto compute = [&](int s) {
    bf16x8 af[4], bf[4];
#pragma unroll
    for (int i = 0; i < 4; i++)
      af[i] = *(const bf16x8*)&As[s][(wm + i * 16 + m_l) * 32 + quad * 8];
#pragma unroll
    for (int j = 0; j < 4; j++)
      bf[j] = *(const bf16x8*)&Bs[s][(wn + j * 16 + m_l) * 32 + quad * 8];
#pragma unroll
    for (int i = 0; i < 4; i++)
#pragma unroll
      for (int j = 0; j < 4; j++)
        acc[i][j] = __builtin_amdgcn_mfma_f32_16x16x32_bf16(af[i], bf[j], acc[i][j], 0, 0, 0);
  };

  stage(0, 0);
  stage(32, 1);
  int buf = 0;
  // main: loads for compute(buf) aged two compute phases at their vmcnt wait.
  for (int k0 = 0; k0 + 64 < K; k0 += 32) {
    int pre = buf + 2; if (pre >= 3) pre -= 3;
    stage(k0 + 64, pre);
    VMCNT(8);                           // 12 outstanding -> oldest stage done
    __builtin_amdgcn_s_barrier();
    compute(buf);
    __builtin_amdgcn_s_barrier();       // WAR: all waves done reading buf
    buf = (buf + 1 == 3) ? 0 : buf + 1;
  }
  VMCNT(4);                             // tail 1: second-to-last buffer ready
  __builtin_amdgcn_s_barrier();
  compute(buf);
  __builtin_amdgcn_s_barrier();
  buf = (buf + 1 == 3) ? 0 : buf + 1;
  VMCNT(0);                             // tail 2: last buffer ready
  __builtin_amdgcn_s_barrier();
  compute(buf);

  float bv[4];
#pragma unroll
  for (int j = 0; j < 4; j++) bv[j] = bias[blockIdx.x * 128 + wn + j * 16 + m_l];
  bool isV = (blockIdx.x >= 16);             // V columns: n in [2048,3072)
  int bb = (blockIdx.y * 128) >> 11;          // batch index, block-uniform
  unsigned short* vbase = vtp + (size_t)bb * 16 * 64 * 2048;
#pragma unroll
  for (int i = 0; i < 4; i++) {
    int m = blockIdx.y * 128 + wm + i * 16 + quad * 4;
    int s = m & 2047;
#pragma unroll
    for (int j = 0; j < 4; j++) {
      int n = blockIdx.x * 128 + wn + j * 16 + m_l;
      float sc = (n < qcols) ? qscale : 1.0f;
      int nv = n - 2048;                     // = h*64+d when isV
#pragma unroll
      for (int r = 0; r < 4; r++) {
        float v = (acc[i][j][r] + bv[j]) * sc;
        unsigned short hv = f2b(v);
        Cp[(size_t)(m + r) * N + n] = hv;
        if (isV) vbase[(size_t)nv * 2048 + s + r] = hv;
      }
    }
  }
}

// ---------------------------------------------------------------------------
// GEMM2: C[M,N] = A[M,K]*Bt[N,K]^T + bias[N], fp32 out.
// 128x128 tile, 512 thr = 8 waves (2 wm x 4 wn), each 64x32 output.
// R17: 3-buffer distance-2 pipeline (2 loads/stage). Grid (8,32)=256 blocks.
// ---------------------------------------------------------------------------
__global__ __launch_bounds__(512) void gemm_bt2(
    const unsigned short* __restrict__ A, const unsigned short* __restrict__ Bt,
    const float* __restrict__ bias, float* __restrict__ Cp, int M, int N, int K) {
  __shared__ __align__(16) unsigned short As[3][128 * 32];
  __shared__ __align__(16) unsigned short Bs[3][128 * 32];
  int tid = threadIdx.x;
  int wave = tid >> 6, lane = tid & 63;
  int m_l = lane & 15, quad = lane >> 4;
  int wm = (wave >> 2) * 64, wn = (wave & 3) * 32;
  int row = tid >> 2, kp = (tid & 3) << 3;    // 128 rows x 4 chunks of 16B
  const unsigned short* ag = A + (size_t)(blockIdx.y * 128 + row) * K + kp;
  const unsigned short* bg = Bt + (size_t)(blockIdx.x * 128 + row) * K + kp;
  f32x4 acc[4][2] = {};

  auto stage = [&](int k0, int s) {     // 2 loads/wave -> vmcnt +2
    gl_lds16(ag + k0, &As[s][wave * 512]);
    gl_lds16(bg + k0, &Bs[s][wave * 512]);
  };
  auto compute = [&](int s) {
    bf16x8 af[4], bf[2];
#pragma unroll
    for (int i = 0; i < 4; i++)
      af[i] = *(const bf16x8*)&As[s][(wm + i * 16 + m_l) * 32 + quad * 8];
#pragma unroll
    for (int j = 0; j < 2; j++)
      bf[j] = *(const bf16x8*)&Bs[s][(wn + j * 16 + m_l) * 32 + quad * 8];
#pragma unroll
    for (int i = 0; i < 4; i++)
#pragma unroll
      for (int j = 0; j < 2; j++)
        acc[i][j] = __builtin_amdgcn_mfma_f32_16x16x32_bf16(af[i], bf[j], acc[i][j], 0, 0, 0);
  };

  stage(0, 0);
  stage(32, 1);
  int buf = 0;
  for (int k0 = 0; k0 + 64 < K; k0 += 32) {
    int pre = buf + 2; if (pre >= 3) pre -= 3;
    stage(k0 + 64, pre);
    VMCNT(4);                           // 6 outstanding -> oldest stage done
    __builtin_amdgcn_s_barrier();
    compute(buf);
    __builtin_amdgcn_s_barrier();
    buf = (buf + 1 == 3) ? 0 : buf + 1;
  }
  VMCNT(2);
  __builtin_amdgcn_s_barrier();
  compute(buf);
  __builtin_amdgcn_s_barrier();
  buf = (buf + 1 == 3) ? 0 : buf + 1;
  VMCNT(0);
  __builtin_amdgcn_s_barrier();
  compute(buf);

  float bv[2];
#pragma unroll
  for (int j = 0; j < 2; j++) bv[j] = bias[blockIdx.x * 128 + wn + j * 16 + m_l];
#pragma unroll
  for (int i = 0; i < 4; i++) {
    int m = blockIdx.y * 128 + wm + i * 16 + quad * 4;
#pragma unroll
    for (int j = 0; j < 2; j++) {
      int n = blockIdx.x * 128 + wn + j * 16 + m_l;
#pragma unroll
      for (int r = 0; r < 4; r++)
        Cp[(size_t)(m + r) * N + n] = acc[i][j][r] + bv[j];
    }
  }
}

// ---------------------------------------------------------------------------
// Flash attention, 32x32x16 MFMA (fragments HW-verified R10/R11).
// 512 threads = 8 waves. Waves w and w+4 own q-group (w&3); wave w handles
// keys [kt,kt+64), wave w+4 keys [kt+64,kt+128) per 128-key round (16 rounds).
// Grid 512 -> 2 blocks/CU, 16 waves/CU (80KB LDS = exactly 2 blocks/CU).
// Double-buffered K/V: stage(next) || compute(cur), ONE __syncthreads/round.
// Hoisted z16 zero C-operand. End: waves 4-7 publish partials; 0-3 combine.
// ---------------------------------------------------------------------------
__global__ __launch_bounds__(512, 4) void attn_kernel(
    const unsigned short* __restrict__ qkv, const unsigned short* __restrict__ vt,
    unsigned short* __restrict__ aout) {
  // 80 KB: Qs[128][64] | Ks[2][128][64] | Vts[2][64][128]  (shorts)
  __shared__ __align__(16) unsigned short smem[40960];
  unsigned short* Qs  = smem;           // 8192 shorts
  unsigned short* Ks0 = smem + 8192;    // 8192
  unsigned short* Ks1 = smem + 16384;   // 8192
  unsigned short* Vt0 = smem + 24576;   // 8192
  unsigned short* Vt1 = smem + 32768;   // 8192

  int bid = blockIdx.x;
  int qt = bid & 15, h = (bid >> 4) & 15, b = bid >> 8;
  int tid = threadIdx.x, wave = tid >> 6, lane = tid & 63;
  int l31 = lane & 31, hi = lane >> 5, l7 = lane & 7;
  int w03 = wave & 3;                 // q-group
  int koff = (wave >> 2) * 64;        // key half within the 128-key round
  int q0 = qt * 128;
  const unsigned short* qb = qkv + (size_t)b * 2048 * 3072 + h * 64;
  const unsigned short* kb = qb + 1024;
  const unsigned short* vtb = vt + (size_t)(b * 16 + h) * 64 * 2048;

  // K/Q staging: 512 threads cover 64 rows x 8 chunks; source chunk
  // (tid&7)^(row&7) so LDS[row][slot c] holds global chunk c^(row&7).
  int srow = tid >> 3;                      // 0..63
  int sd0 = ((tid & 7) ^ (srow & 7)) * 8;
  // V staging: 512 threads cover 32 d-rows x 16 chunks; slot s holds global
  // chunk (s&8) | ((s&7)^(d&7)).
  int dv = tid >> 4;                        // 0..31
  int sv = tid & 15;
  int gv = (sv & 8) | ((sv & 7) ^ (dv & 7));

  auto stageKV = [&](unsigned short* Kb, unsigned short* Vb, int kt) {
    gl_lds16(kb + (size_t)(kt + srow) * 3072 + sd0, Kb + wave * 512);
    gl_lds16(kb + (size_t)(kt + 64 + srow) * 3072 + sd0, Kb + 4096 + wave * 512);
    gl_lds16(vtb + (size_t)dv * 2048 + kt + gv * 8, Vb + wave * 512);
    gl_lds16(vtb + (size_t)(32 + dv) * 2048 + kt + gv * 8, Vb + 4096 + wave * 512);
  };

  // stage Q[128][64] (2 rounds of 64 rows) + first K/V buffer
#pragma unroll
  for (int p = 0; p < 2; p++)
    gl_lds16(qb + (size_t)(q0 + p * 64 + srow) * 3072 + sd0, Qs + p * 4096 + wave * 512);
  stageKV(Ks0, Vt0, 0);
  __syncthreads();

  // Q B-frags (hoisted): q = w03*32 + l31; k-slice ks: chunk 2*ks+hi
  bf16x8 qf[4];
  int qrow = (w03 * 32 + l31) * 64;
#pragma unroll
  for (int ks = 0; ks < 4; ks++)
    qf[ks] = *(const bf16x8*)&Qs[qrow + ((2 * ks + hi) ^ l7) * 8];

  union { s16x8 s; bf16x8 v; } onesu;
  onesu.s = (s16x8){0x3F80, 0x3F80, 0x3F80, 0x3F80, 0x3F80, 0x3F80, 0x3F80, 0x3F80};

  f32x16 oacc[2] = {};   // O^T partial accumulators, dtile = d/32
  f32x16 lacc = {};      // lp partial via ones-MFMA (all regs = column sum)
  f32x16 z16 = {};       // hoisted zero C-operand

  auto computeKV = [&](const unsigned short* Kb, const unsigned short* Vb) {
#pragma unroll
    for (int tt = 0; tt < 2; tt++) {
      // S^T[key 32][q 32] for this wave's keytile (koff + tt*32)
      bf16x8 kf0 = *(const bf16x8*)&Kb[(koff + tt * 32 + l31) * 64 + ((2 * 0 + hi) ^ l7) * 8];
      f32x16 sacc = __builtin_amdgcn_mfma_f32_32x32x16_bf16(kf0, qf[0], z16, 0, 0, 0);
#pragma unroll
      for (int ks = 1; ks < 4; ks++) {
        bf16x8 kf = *(const bf16x8*)&Kb[(koff + tt * 32 + l31) * 64 + ((2 * ks + hi) ^ l7) * 8];
        sacc = __builtin_amdgcn_mfma_f32_32x32x16_bf16(kf, qf[ks], sacc, 0, 0, 0);
      }
      float pv[16];
#pragma unroll
      for (int i = 0; i < 16; i++) pv[i] = __builtin_exp2f(sacc[i]);
#pragma unroll
      for (int g = 0; g < 2; g++) {
        // own regs 8g..8g+3 -> rows 16g+4hi+{0..3}; 8g+4..8g+7 -> 16g+8+4hi+{0..3}
        unsigned a0 = cvt_pk_bf16(pv[8 * g + 0], pv[8 * g + 1]);
        unsigned a1 = cvt_pk_bf16(pv[8 * g + 2], pv[8 * g + 3]);
        unsigned b0 = cvt_pk_bf16(pv[8 * g + 4], pv[8 * g + 5]);
        unsigned b1 = cvt_pk_bf16(pv[8 * g + 6], pv[8 * g + 7]);
        permlane32_swap(a0, b0);  // a0={keys 16g+8hi+0,1}, b0={keys 16g+8hi+4,5}
        permlane32_swap(a1, b1);  // a1={keys 16g+8hi+2,3}, b1={keys 16g+8hi+6,7}
        union { unsigned u[4]; bf16x8 v; } pf;
        pf.u[0] = a0; pf.u[1] = a1; pf.u[2] = b0; pf.u[3] = b1;
        lacc = __builtin_amdgcn_mfma_f32_32x32x16_bf16(onesu.v, pf.v, lacc, 0, 0, 0);
        int kc = tt * 2 + g;      // 16-key slice within this wave's 64-key half
#pragma unroll
        for (int dt = 0; dt < 2; dt++) {
          bf16x8 vf = *(const bf16x8*)&Vb[(dt * 32 + l31) * 128 +
                                          ((koff >> 3) | ((kc * 2 + hi) ^ l7)) * 8];
          oacc[dt] = __builtin_amdgcn_mfma_f32_32x32x16_bf16(vf, pf.v, oacc[dt], 0, 0, 0);
        }
      }
    }
  };

  // 16 rounds of 128 keys, unrolled x2 for static buffer selection.
  for (int kt = 0; kt < 2048; kt += 256) {
    stageKV(Ks1, Vt1, kt + 128);          // async prefetch next round
    __builtin_amdgcn_s_setprio(1);
    computeKV(Ks0, Vt0);
    __builtin_amdgcn_s_setprio(0);
    __syncthreads();                       // drains prefetch (aged a full phase)
    if (kt + 256 < 2048) stageKV(Ks0, Vt0, kt + 256);
    __builtin_amdgcn_s_setprio(1);
    computeKV(Ks1, Vt1);
    __builtin_amdgcn_s_setprio(0);
    __syncthreads();
  }

  // pair-combine: waves 4-7 publish partials; waves 0-3 add + store.
  float* red = (float*)smem;   // scratch; layout: 4 groups x 2048 f32 + lp
  float* lpred = red + 8192;
  if (wave >= 4) {
    float* basep = red + w03 * 2048;
#pragma unroll
    for (int dt = 0; dt < 2; dt++)
#pragma unroll
      for (int r = 0; r < 4; r++) {
        f32x4 c4 = {oacc[dt][4 * r + 0], oacc[dt][4 * r + 1],
                    oacc[dt][4 * r + 2], oacc[dt][4 * r + 3]};
        ((f32x4*)basep)[lane * 8 + ((dt * 4 + r) ^ (lane & 7))] = c4;
      }
    lpred[w03 * 64 + lane] = lacc[0];
  }
  __syncthreads();
  if (wave < 4) {
    float* basep = red + w03 * 2048;
#pragma unroll
    for (int dt = 0; dt < 2; dt++)
#pragma unroll
      for (int r = 0; r < 4; r++) {
        f32x4 c4 = ((f32x4*)basep)[lane * 8 + ((dt * 4 + r) ^ (lane & 7))];
        oacc[dt][4 * r + 0] += c4[0];
        oacc[dt][4 * r + 1] += c4[1];
        oacc[dt][4 * r + 2] += c4[2];
        oacc[dt][4 * r + 3] += c4[3];
      }
    float rl = 1.0f / (lacc[0] + lpred[w03 * 64 + lane]);

    // epilogue: O^T frag col=q=l31, row d = 32*dt + 8*(reg>>2) + 4*hi + (reg&3)
    unsigned short* ob = aout + (size_t)(b * 2048 + q0 + w03 * 32 + l31) * 1024 + h * 64;
#pragma unroll
    for (int dt = 0; dt < 2; dt++)
#pragma unroll
      for (int rq = 0; rq < 4; rq++) {
        union { uint2 u; ushort4 w; } pk;
        pk.u.x = cvt_pk_bf16(oacc[dt][4 * rq + 0] * rl, oacc[dt][4 * rq + 1] * rl);
        pk.u.y = cvt_pk_bf16(oacc[dt][4 * rq + 2] * rl, oacc[dt][4 * rq + 3] * rl);
        *(ushort4*)&ob[dt * 32 + rq * 8 + hi * 4] = pk.w;
      }
  }
}

// ---------------------------------------------------------------------------
extern "C" void kernel_launch(void* const* d_in, const int* in_sizes, int n_in,
                              void* d_out, int out_size, void* d_ws, size_t ws_size,
                              hipStream_t stream) {
  (void)in_sizes; (void)n_in; (void)out_size; (void)ws_size;
  const float* x     = (const float*)d_in[0];
  const float* w_in  = (const float*)d_in[1];
  const float* b_in  = (const float*)d_in[2];
  const float* w_out = (const float*)d_in[3];
  const float* b_out = (const float*)d_in[4];
  char* ws = (char*)d_ws;
  unsigned short* xb    = (unsigned short*)(ws + 0);          //  8 MB
  unsigned short* wint  = (unsigned short*)(ws + 8388608);    //  6 MB
  unsigned short* woutt = (unsigned short*)(ws + 14680064);   //  2 MB
  unsigned short* qkv   = (unsigned short*)(ws + 16777216);   // 24 MB
  unsigned short* vt    = (unsigned short*)(ws + 41943040);   //  8 MB
  unsigned short* attn  = (unsigned short*)(ws + 50331648);   //  8 MB
  float* out = (float*)d_out;

  const float QSCALE = 0.125f * 1.44269504088896f;  // fold 1/sqrt(64) * log2(e)

  prep_kernel<<<5120, 256, 0, stream>>>(x, xb, w_in, wint, w_out, woutt);
  gemm_bt1<<<dim3(24, 32), 256, 0, stream>>>(xb, wint, b_in, qkv, vt,
                                             4096, 3072, 1024, 1024, QSCALE);
  attn_kernel<<<512, 512, 0, stream>>>(qkv, vt, attn);
  gemm_bt2<<<dim3(8, 32), 512, 0, stream>>>(attn, woutt, b_out, out, 4096, 1024, 1024);
}

// Round 9
// 197.766 us; speedup vs baseline: 1.0003x; 1.0003x over previous
//
#include <hip/hip_runtime.h>

// ---------------------------------------------------------------------------
// MultiHeadAttention: B=2, S=2048, E=1024, H=16, D=64
//   1. prep_kernel (fused): cast x->bf16; transpose+cast w_in, w_out
//      (float4 loads, ushort2 stores).
//   2. GEMM1: qkv[4096,3072] = x @ w_in + b_in (bf16; Q cols pre-scaled by
//      0.125*log2e); V-transpose fused into epilogue (R14).
//      R18: reverted to R16 2-phase dbuf (1 barrier/k-step; R17's 2-barrier
//      distance-2 regressed). 3 blocks/CU preserved (32KB LDS).
//   3. flash attention — 32x32x16 MFMA, wave-pair key-split, dbuf K/V,
//      setprio, hoisted zero C-operand (R10-R13, all HW-verified).
//   4. GEMM2: out = attn @ w_out + b_out. 128x128 tile, 512 thr.
//      R18: 4-buffer prefetch-distance-2 with ONE barrier/k-step
//      (stage(i+2); vmcnt(4); s_barrier; compute(i)) — WAR safe because
//      buffer (i+2)%4 was last read at compute(i-2), behind barrier(i-1).
//      64KB LDS is free here: 256 blocks = 1 block/CU regardless.
// ---------------------------------------------------------------------------

typedef __bf16 bf16x8 __attribute__((ext_vector_type(8)));
typedef float  f32x4  __attribute__((ext_vector_type(4)));
typedef float  f32x16 __attribute__((ext_vector_type(16)));
typedef short  s16x8  __attribute__((ext_vector_type(8)));

__device__ __forceinline__ unsigned short f2b(float f) {
  unsigned u = __float_as_uint(f);
  unsigned r = u + 0x7fffu + ((u >> 16) & 1u);   // round-to-nearest-even
  return (unsigned short)(r >> 16);
}

// gfx950 HW packed fp32->bf16 convert (RNE): low16=cvt(a), high16=cvt(b).
__device__ __forceinline__ unsigned cvt_pk_bf16(float a, float b) {
#if defined(__HIP_DEVICE_COMPILE__)
  unsigned r;
  asm("v_cvt_pk_bf16_f32 %0, %1, %2" : "=v"(r) : "v"(a), "v"(b));
  return r;
#else
  return (unsigned)f2b(a) | ((unsigned)f2b(b) << 16);
#endif
}

// v_permlane32_swap_b32 a, b:  a' = {a_lo, b_lo}, b' = {a_hi, b_hi}
__device__ __forceinline__ void permlane32_swap(unsigned& a, unsigned& b) {
#if defined(__HIP_DEVICE_COMPILE__)
  asm("v_permlane32_swap_b32 %0, %1" : "+v"(a), "+v"(b));
#endif
}

// async global->LDS, 16 bytes per lane; HW writes lane i at lds + i*16.
__device__ __forceinline__ void gl_lds16(const void* g, void* l) {
  __builtin_amdgcn_global_load_lds(
      (__attribute__((address_space(1))) void*)g,
      (__attribute__((address_space(3))) void*)l, 16, 0, 0);
}

#define VMCNT(n) asm volatile("s_waitcnt vmcnt(" #n ")" ::: "memory")

// ---------------------------------------------------------------------------
// prep_kernel: fused elementwise cast (x->xb) + two transpose_cast jobs.
// grid 5120 x 256: [0,4096) cast; [4096,4864) w_in T; [4864,5120) w_out T.
// ---------------------------------------------------------------------------
__device__ __forceinline__ void transpose_cast_body(
    const float* __restrict__ in, unsigned short* __restrict__ out,
    int R, int C, int bx, int by, int tid, float tile[64][65]) {
  int r0 = by * 64, c0 = bx * 64;
#pragma unroll
  for (int p = 0; p < 4; p++) {
    int i = tid + p * 256;              // 0..1023: 64 rows x 16 float4
    int ri = i >> 4, c4 = (i & 15) * 4;
    float4 v = *(const float4*)&in[(size_t)(r0 + ri) * C + c0 + c4];
    tile[ri][c4 + 0] = v.x; tile[ri][c4 + 1] = v.y;
    tile[ri][c4 + 2] = v.z; tile[ri][c4 + 3] = v.w;
  }
  __syncthreads();
#pragma unroll
  for (int p = 0; p < 8; p++) {
    int i = tid + p * 256;              // 0..2047: 64 cols x 32 row-pairs
    int ci = i >> 5, rp = (i & 31) * 2;
    ushort2 o;
    o.x = f2b(tile[rp][ci]);
    o.y = f2b(tile[rp + 1][ci]);
    *(ushort2*)&out[(size_t)(c0 + ci) * R + r0 + rp] = o;
  }
}

__global__ __launch_bounds__(256) void prep_kernel(
    const float* __restrict__ x, unsigned short* __restrict__ xb,
    const float* __restrict__ w_in, unsigned short* __restrict__ wint,
    const float* __restrict__ w_out, unsigned short* __restrict__ woutt) {
  __shared__ float tile[64][65];
  int bid = blockIdx.x, tid = threadIdx.x;
  if (bid < 4096) {
    int i = bid * 256 + tid;   // n4 = 1048576 exactly = 4096*256
    float4 v = ((const float4*)x)[i];
    ushort4 o;
    o.x = f2b(v.x); o.y = f2b(v.y); o.z = f2b(v.z); o.w = f2b(v.w);
    ((ushort4*)xb)[i] = o;
  } else if (bid < 4864) {
    int l = bid - 4096;        // 768 blocks: (48 x, 16 y)
    transpose_cast_body(w_in, wint, 1024, 3072, l % 48, l / 48, tid, tile);
  } else {
    int l = bid - 4864;        // 256 blocks: (16 x, 16 y)
    transpose_cast_body(w_out, woutt, 1024, 1024, l % 16, l / 16, tid, tile);
  }
}

// ---------------------------------------------------------------------------
// GEMM1: C[M,N] = A[M,K]*Bt[N,K]^T + bias[N], bf16 out. 128x128 tile, BK=32.
// R16 structure: 2-buffer dbuf, stage(next) || compute(cur), 1 barrier/step.
// Blocks with bx>=16 (V cols) also scatter to vt[((b*16+h)*64+d)*2048+s].
// ---------------------------------------------------------------------------
__global__ __launch_bounds__(256) void gemm_bt1(
    const unsigned short* __restrict__ A, const unsigned short* __restrict__ Bt,
    const float* __restrict__ bias, unsigned short* __restrict__ Cp,
    unsigned short* __restrict__ vtp,
    int M, int N, int K, int qcols, float qscale) {
  __shared__ __align__(16) unsigned short As[2][128 * 32];   // 2 x 8KB
  __shared__ __align__(16) unsigned short Bs[2][128 * 32];   // 2 x 8KB
  int tid = threadIdx.x;
  int wave = tid >> 6, lane = tid & 63;
  int m_l = lane & 15, quad = lane >> 4;
  int wm = (wave >> 1) * 64, wn = (wave & 1) * 64;
  int row = tid >> 2, kp = (tid & 3) << 3;
  const unsigned short* ag = A + (size_t)(blockIdx.y * 128 + row) * K + kp;
  const unsigned short* bg = Bt + (size_t)(blockIdx.x * 128 + row) * K + kp;
  f32x4 acc[4][4] = {};

  auto stage = [&](int k0, int s) {
    gl_lds16(ag + k0, &As[s][wave * 512]);
    gl_lds16(ag + (size_t)64 * K + k0, &As[s][2048 + wave * 512]);
    gl_lds16(bg + k0, &Bs[s][wave * 512]);
    gl_lds16(bg + (size_t)64 * K + k0, &Bs[s][2048 + wave * 512]);
  };
  auto compute = [&](int s) {
    bf16x8 af[4], bf[4];
#pragma unroll
    for (int i = 0; i < 4; i++)
      af[i] = *(const bf16x8*)&As[s][(wm + i * 16 + m_l) * 32 + quad * 8];
#pragma unroll
    for (int j = 0; j < 4; j++)
      bf[j] = *(const bf16x8*)&Bs[s][(wn + j * 16 + m_l) * 32 + quad * 8];
#pragma unroll
    for (int i = 0; i < 4; i++)
#pragma unroll
      for (int j = 0; j < 4; j++)
        acc[i][j] = __builtin_amdgcn_mfma_f32_16x16x32_bf16(af[i], bf[j], acc[i][j], 0, 0, 0);
  };

  stage(0, 0);
  __syncthreads();
  for (int k0 = 0; k0 < K; k0 += 64) {
    if (k0 + 32 < K) stage(k0 + 32, 1);
    compute(0);
    __syncthreads();
    if (k0 + 64 < K) stage(k0 + 64, 0);
    compute(1);
    __syncthreads();
  }

  float bv[4];
#pragma unroll
  for (int j = 0; j < 4; j++) bv[j] = bias[blockIdx.x * 128 + wn + j * 16 + m_l];
  bool isV = (blockIdx.x >= 16);             // V columns: n in [2048,3072)
  int bb = (blockIdx.y * 128) >> 11;          // batch index, block-uniform
  unsigned short* vbase = vtp + (size_t)bb * 16 * 64 * 2048;
#pragma unroll
  for (int i = 0; i < 4; i++) {
    int m = blockIdx.y * 128 + wm + i * 16 + quad * 4;
    int s = m & 2047;
#pragma unroll
    for (int j = 0; j < 4; j++) {
      int n = blockIdx.x * 128 + wn + j * 16 + m_l;
      float sc = (n < qcols) ? qscale : 1.0f;
      int nv = n - 2048;                     // = h*64+d when isV
#pragma unroll
      for (int r = 0; r < 4; r++) {
        float v = (acc[i][j][r] + bv[j]) * sc;
        unsigned short hv = f2b(v);
        Cp[(size_t)(m + r) * N + n] = hv;
        if (isV) vbase[(size_t)nv * 2048 + s + r] = hv;
      }
    }
  }
}

// ---------------------------------------------------------------------------
// GEMM2: C[M,N] = A[M,K]*Bt[N,K]^T + bias[N], fp32 out.
// 128x128 tile, 512 thr = 8 waves (2 wm x 4 wn), each 64x32 output.
// R18: 4-buffer prefetch-distance-2, ONE barrier per k-step:
//   stage((i+2)&3); vmcnt(4); s_barrier; compute(i&3)
// vmcnt(4): worst-case 6 outstanding (3 stages x 2 loads) -> oldest retired.
// Grid (8,32)=256 blocks = 1 block/CU; 64KB LDS costs nothing here.
// ---------------------------------------------------------------------------
__global__ __launch_bounds__(512) void gemm_bt2(
    const unsigned short* __restrict__ A, const unsigned short* __restrict__ Bt,
    const float* __restrict__ bias, float* __restrict__ Cp, int M, int N, int K) {
  __shared__ __align__(16) unsigned short As[4][128 * 32];   // 4 x 8KB
  __shared__ __align__(16) unsigned short Bs[4][128 * 32];   // 4 x 8KB
  int tid = threadIdx.x;
  int wave = tid >> 6, lane = tid & 63;
  int m_l = lane & 15, quad = lane >> 4;
  int wm = (wave >> 2) * 64, wn = (wave & 3) * 32;
  int row = tid >> 2, kp = (tid & 3) << 3;    // 128 rows x 4 chunks of 16B
  const unsigned short* ag = A + (size_t)(blockIdx.y * 128 + row) * K + kp;
  const unsigned short* bg = Bt + (size_t)(blockIdx.x * 128 + row) * K + kp;
  f32x4 acc[4][2] = {};

  auto stage = [&](int k0, int s) {     // 2 loads/wave
    gl_lds16(ag + k0, &As[s][wave * 512]);
    gl_lds16(bg + k0, &Bs[s][wave * 512]);
  };
  auto compute = [&](int s) {
    bf16x8 af[4], bf[2];
#pragma unroll
    for (int i = 0; i < 4; i++)
      af[i] = *(const bf16x8*)&As[s][(wm + i * 16 + m_l) * 32 + quad * 8];
#pragma unroll
    for (int j = 0; j < 2; j++)
      bf[j] = *(const bf16x8*)&Bs[s][(wn + j * 16 + m_l) * 32 + quad * 8];
#pragma unroll
    for (int i = 0; i < 4; i++)
#pragma unroll
      for (int j = 0; j < 2; j++)
        acc[i][j] = __builtin_amdgcn_mfma_f32_16x16x32_bf16(af[i], bf[j], acc[i][j], 0, 0, 0);
  };

  int nstep = K >> 5;                    // 32 k-steps
  stage(0, 0);
  stage(32, 1);
  for (int i = 0; i < nstep; ++i) {
    if (i + 2 < nstep) {
      stage((i + 2) << 5, (i + 2) & 3);
      VMCNT(4);                          // oldest stage (compute's buf) done
    } else if (i + 1 < nstep) {
      VMCNT(2);
    } else {
      VMCNT(0);
    }
    __builtin_amdgcn_s_barrier();
    compute(i & 3);
  }

  float bv[2];
#pragma unroll
  for (int j = 0; j < 2; j++) bv[j] = bias[blockIdx.x * 128 + wn + j * 16 + m_l];
#pragma unroll
  for (int i = 0; i < 4; i++) {
    int m = blockIdx.y * 128 + wm + i * 16 + quad * 4;
#pragma unroll
    for (int j = 0; j < 2; j++) {
      int n = blockIdx.x * 128 + wn + j * 16 + m_l;
#pragma unroll
      for (int r = 0; r < 4; r++)
        Cp[(size_t)(m + r) * N + n] = acc[i][j][r] + bv[j];
    }
  }
}

// ---------------------------------------------------------------------------
// Flash attention, 32x32x16 MFMA (fragments HW-verified R10/R11).
// 512 threads = 8 waves. Waves w and w+4 own q-group (w&3); wave w handles
// keys [kt,kt+64), wave w+4 keys [kt+64,kt+128) per 128-key round (16 rounds).
// Grid 512 -> 2 blocks/CU, 16 waves/CU (80KB LDS = exactly 2 blocks/CU).
// Double-buffered K/V: stage(next) || compute(cur), ONE __syncthreads/round.
// Hoisted z16 zero C-operand. End: waves 4-7 publish partials; 0-3 combine.
// ---------------------------------------------------------------------------
__global__ __launch_bounds__(512, 4) void attn_kernel(
    const unsigned short* __restrict__ qkv, const unsigned short* __restrict__ vt,
    unsigned short* __restrict__ aout) {
  // 80 KB: Qs[128][64] | Ks[2][128][64] | Vts[2][64][128]  (shorts)
  __shared__ __align__(16) unsigned short smem[40960];
  unsigned short* Qs  = smem;           // 8192 shorts
  unsigned short* Ks0 = smem + 8192;    // 8192
  unsigned short* Ks1 = smem + 16384;   // 8192
  unsigned short* Vt0 = smem + 24576;   // 8192
  unsigned short* Vt1 = smem + 32768;   // 8192

  int bid = blockIdx.x;
  int qt = bid & 15, h = (bid >> 4) & 15, b = bid >> 8;
  int tid = threadIdx.x, wave = tid >> 6, lane = tid & 63;
  int l31 = lane & 31, hi = lane >> 5, l7 = lane & 7;
  int w03 = wave & 3;                 // q-group
  int koff = (wave >> 2) * 64;        // key half within the 128-key round
  int q0 = qt * 128;
  const unsigned short* qb = qkv + (size_t)b * 2048 * 3072 + h * 64;
  const unsigned short* kb = qb + 1024;
  const unsigned short* vtb = vt + (size_t)(b * 16 + h) * 64 * 2048;

  // K/Q staging: 512 threads cover 64 rows x 8 chunks; source chunk
  // (tid&7)^(row&7) so LDS[row][slot c] holds global chunk c^(row&7).
  int srow = tid >> 3;                      // 0..63
  int sd0 = ((tid & 7) ^ (srow & 7)) * 8;
  // V staging: 512 threads cover 32 d-rows x 16 chunks; slot s holds global
  // chunk (s&8) | ((s&7)^(d&7)).
  int dv = tid >> 4;                        // 0..31
  int sv = tid & 15;
  int gv = (sv & 8) | ((sv & 7) ^ (dv & 7));

  auto stageKV = [&](unsigned short* Kb, unsigned short* Vb, int kt) {
    gl_lds16(kb + (size_t)(kt + srow) * 3072 + sd0, Kb + wave * 512);
    gl_lds16(kb + (size_t)(kt + 64 + srow) * 3072 + sd0, Kb + 4096 + wave * 512);
    gl_lds16(vtb + (size_t)dv * 2048 + kt + gv * 8, Vb + wave * 512);
    gl_lds16(vtb + (size_t)(32 + dv) * 2048 + kt + gv * 8, Vb + 4096 + wave * 512);
  };

  // stage Q[128][64] (2 rounds of 64 rows) + first K/V buffer
#pragma unroll
  for (int p = 0; p < 2; p++)
    gl_lds16(qb + (size_t)(q0 + p * 64 + srow) * 3072 + sd0, Qs + p * 4096 + wave * 512);
  stageKV(Ks0, Vt0, 0);
  __syncthreads();

  // Q B-frags (hoisted): q = w03*32 + l31; k-slice ks: chunk 2*ks+hi
  bf16x8 qf[4];
  int qrow = (w03 * 32 + l31) * 64;
#pragma unroll
  for (int ks = 0; ks < 4; ks++)
    qf[ks] = *(const bf16x8*)&Qs[qrow + ((2 * ks + hi) ^ l7) * 8];

  union { s16x8 s; bf16x8 v; } onesu;
  onesu.s = (s16x8){0x3F80, 0x3F80, 0x3F80, 0x3F80, 0x3F80, 0x3F80, 0x3F80, 0x3F80};

  f32x16 oacc[2] = {};   // O^T partial accumulators, dtile = d/32
  f32x16 lacc = {};      // lp partial via ones-MFMA (all regs = column sum)
  f32x16 z16 = {};       // hoisted zero C-operand

  auto computeKV = [&](const unsigned short* Kb, const unsigned short* Vb) {
#pragma unroll
    for (int tt = 0; tt < 2; tt++) {
      // S^T[key 32][q 32] for this wave's keytile (koff + tt*32)
      bf16x8 kf0 = *(const bf16x8*)&Kb[(koff + tt * 32 + l31) * 64 + ((2 * 0 + hi) ^ l7) * 8];
      f32x16 sacc = __builtin_amdgcn_mfma_f32_32x32x16_bf16(kf0, qf[0], z16, 0, 0, 0);
#pragma unroll
      for (int ks = 1; ks < 4; ks++) {
        bf16x8 kf = *(const bf16x8*)&Kb[(koff + tt * 32 + l31) * 64 + ((2 * ks + hi) ^ l7) * 8];
        sacc = __builtin_amdgcn_mfma_f32_32x32x16_bf16(kf, qf[ks], sacc, 0, 0, 0);
      }
      float pv[16];
#pragma unroll
      for (int i = 0; i < 16; i++) pv[i] = __builtin_exp2f(sacc[i]);
#pragma unroll
      for (int g = 0; g < 2; g++) {
        // own regs 8g..8g+3 -> rows 16g+4hi+{0..3}; 8g+4..8g+7 -> 16g+8+4hi+{0..3}
        unsigned a0 = cvt_pk_bf16(pv[8 * g + 0], pv[8 * g + 1]);
        unsigned a1 = cvt_pk_bf16(pv[8 * g + 2], pv[8 * g + 3]);
        unsigned b0 = cvt_pk_bf16(pv[8 * g + 4], pv[8 * g + 5]);
        unsigned b1 = cvt_pk_bf16(pv[8 * g + 6], pv[8 * g + 7]);
        permlane32_swap(a0, b0);  // a0={keys 16g+8hi+0,1}, b0={keys 16g+8hi+4,5}
        permlane32_swap(a1, b1);  // a1={keys 16g+8hi+2,3}, b1={keys 16g+8hi+6,7}
        union { unsigned u[4]; bf16x8 v; } pf;
        pf.u[0] = a0; pf.u[1] = a1; pf.u[2] = b0; pf.u[3] = b1;
        lacc = __builtin_amdgcn_mfma_f32_32x32x16_bf16(onesu.v, pf.v, lacc, 0, 0, 0);
        int kc = tt * 2 + g;      // 16-key slice within this wave's 64-key half
#pragma unroll
        for (int dt = 0; dt < 2; dt++) {
          bf16x8 vf = *(const bf16x8*)&Vb[(dt * 32 + l31) * 128 +
                                          ((koff >> 3) | ((kc * 2 + hi) ^ l7)) * 8];
          oacc[dt] = __builtin_amdgcn_mfma_f32_32x32x16_bf16(vf, pf.v, oacc[dt], 0, 0, 0);
        }
      }
    }
  };

  // 16 rounds of 128 keys, unrolled x2 for static buffer selection.
  for (int kt = 0; kt < 2048; kt += 256) {
    stageKV(Ks1, Vt1, kt + 128);          // async prefetch next round
    __builtin_amdgcn_s_setprio(1);
    computeKV(Ks0, Vt0);
    __builtin_amdgcn_s_setprio(0);
    __syncthreads();                       // drains prefetch (aged a full phase)
    if (kt + 256 < 2048) stageKV(Ks0, Vt0, kt + 256);
    __builtin_amdgcn_s_setprio(1);
    computeKV(Ks1, Vt1);
    __builtin_amdgcn_s_setprio(0);
    __syncthreads();
  }

  // pair-combine: waves 4-7 publish partials; waves 0-3 add + store.
  float* red = (float*)smem;   // scratch; layout: 4 groups x 2048 f32 + lp
  float* lpred = red + 8192;
  if (wave >= 4) {
    float* basep = red + w03 * 2048;
#pragma unroll
    for (int dt = 0; dt < 2; dt++)
#pragma unroll
      for (int r = 0; r < 4; r++) {
        f32x4 c4 = {oacc[dt][4 * r + 0], oacc[dt][4 * r + 1],
                    oacc[dt][4 * r + 2], oacc[dt][4 * r + 3]};
        ((f32x4*)basep)[lane * 8 + ((dt * 4 + r) ^ (lane & 7))] = c4;
      }
    lpred[w03 * 64 + lane] = lacc[0];
  }
  __syncthreads();
  if (wave < 4) {
    float* basep = red + w03 * 2048;
#pragma unroll
    for (int dt = 0; dt < 2; dt++)
#pragma unroll
      for (int r = 0; r < 4; r++) {
        f32x4 c4 = ((f32x4*)basep)[lane * 8 + ((dt * 4 + r) ^ (lane & 7))];
        oacc[dt][4 * r + 0] += c4[0];
        oacc[dt][4 * r + 1] += c4[1];
        oacc[dt][4 * r + 2] += c4[2];
        oacc[dt][4 * r + 3] += c4[3];
      }
    float rl = 1.0f / (lacc[0] + lpred[w03 * 64 + lane]);

    // epilogue: O^T frag col=q=l31, row d = 32*dt + 8*(reg>>2) + 4*hi + (reg&3)
    unsigned short* ob = aout + (size_t)(b * 2048 + q0 + w03 * 32 + l31) * 1024 + h * 64;
#pragma unroll
    for (int dt = 0; dt < 2; dt++)
#pragma unroll
      for (int rq = 0; rq < 4; rq++) {
        union { uint2 u; ushort4 w; } pk;
        pk.u.x = cvt_pk_bf16(oacc[dt][4 * rq + 0] * rl, oacc[dt][4 * rq + 1] * rl);
        pk.u.y = cvt_pk_bf16(oacc[dt][4 * rq + 2] * rl, oacc[dt][4 * rq + 3] * rl);
        *(ushort4*)&ob[dt * 32 + rq * 8 + hi * 4] = pk.w;
      }
  }
}

// ---------------------------------------------------------------------------
extern "C" void kernel_launch(void* const* d_in, const int* in_sizes, int n_in,
                              void* d_out, int out_size, void* d_ws, size_t ws_size,
                              hipStream_t stream) {
  (void)in_sizes; (void)n_in; (void)out_size; (void)ws_size;
  const float* x     = (const float*)d_in[0];
  const float* w_in  = (const float*)d_in[1];
  const float* b_in  = (const float*)d_in[2];
  const float* w_out = (const float*)d_in[3];
  const float* b_out = (const float*)d_in[4];
  char* ws = (char*)d_ws;
  unsigned short* xb    = (unsigned short*)(ws + 0);          //  8 MB
  unsigned short* wint  = (unsigned short*)(ws + 8388608);    //  6 MB
  unsigned short* woutt = (unsigned short*)(ws + 14680064);   //  2 MB
  unsigned short* qkv   = (unsigned short*)(ws + 16777216);   // 24 MB
  unsigned short* vt    = (unsigned short*)(ws + 41943040);   //  8 MB
  unsigned short* attn  = (unsigned short*)(ws + 50331648);   //  8 MB
  float* out = (float*)d_out;

  const float QSCALE = 0.125f * 1.44269504088896f;  // fold 1/sqrt(64) * log2(e)

  prep_kernel<<<5120, 256, 0, stream>>>(x, xb, w_in, wint, w_out, woutt);
  gemm_bt1<<<dim3(24, 32), 256, 0, stream>>>(xb, wint, b_in, qkv, vt,
                                             4096, 3072, 1024, 1024, QSCALE);
  attn_kernel<<<512, 512, 0, stream>>>(qkv, vt, attn);
  gemm_bt2<<<dim3(8, 32), 512, 0, stream>>>(attn, woutt, b_out, out, 4096, 1024, 1024);
}

// Round 10
// 195.644 us; speedup vs baseline: 1.0112x; 1.0108x over previous
//
#include <hip/hip_runtime.h>

// ---------------------------------------------------------------------------
// MultiHeadAttention: B=2, S=2048, E=1024, H=16, D=64
//   1. prep_kernel (fused): cast x->bf16; transpose+cast w_in, w_out
//      (float4 loads, ushort2 stores).
//   2. GEMM1: qkv = x @ w_in + b_in (bf16; Q pre-scaled by 0.125*log2e);
//      V-transpose fused into epilogue (R14); R16 2-phase dbuf.
//      R19: XCD swizzle — each XCD owns 4 complete row-panels (A reuse in L2).
//   3. flash attention — 32x32x16 MFMA, wave-pair key-split, dbuf K/V,
//      setprio, hoisted zero C-operand (R10-R13).
//      R19: XCD swizzle — 16 q-tile blocks sharing one (h,b)'s K/V land on
//      one XCD (K/V becomes L2-resident; fetch ~70MB -> ~30MB predicted).
//   4. GEMM2: out = attn @ w_out + b_out. R16 exact 2-phase structure
//      (R18's 4-buffer dynamic-index pipeline regressed; reverted).
//      R19: XCD swizzle — 4 row-panels per XCD.
// ---------------------------------------------------------------------------

typedef __bf16 bf16x8 __attribute__((ext_vector_type(8)));
typedef float  f32x4  __attribute__((ext_vector_type(4)));
typedef float  f32x16 __attribute__((ext_vector_type(16)));
typedef short  s16x8  __attribute__((ext_vector_type(8)));

__device__ __forceinline__ unsigned short f2b(float f) {
  unsigned u = __float_as_uint(f);
  unsigned r = u + 0x7fffu + ((u >> 16) & 1u);   // round-to-nearest-even
  return (unsigned short)(r >> 16);
}

// gfx950 HW packed fp32->bf16 convert (RNE): low16=cvt(a), high16=cvt(b).
__device__ __forceinline__ unsigned cvt_pk_bf16(float a, float b) {
#if defined(__HIP_DEVICE_COMPILE__)
  unsigned r;
  asm("v_cvt_pk_bf16_f32 %0, %1, %2" : "=v"(r) : "v"(a), "v"(b));
  return r;
#else
  return (unsigned)f2b(a) | ((unsigned)f2b(b) << 16);
#endif
}

// v_permlane32_swap_b32 a, b:  a' = {a_lo, b_lo}, b' = {a_hi, b_hi}
__device__ __forceinline__ void permlane32_swap(unsigned& a, unsigned& b) {
#if defined(__HIP_DEVICE_COMPILE__)
  asm("v_permlane32_swap_b32 %0, %1" : "+v"(a), "+v"(b));
#endif
}

// async global->LDS, 16 bytes per lane; HW writes lane i at lds + i*16.
__device__ __forceinline__ void gl_lds16(const void* g, void* l) {
  __builtin_amdgcn_global_load_lds(
      (__attribute__((address_space(1))) void*)g,
      (__attribute__((address_space(3))) void*)l, 16, 0, 0);
}

// ---------------------------------------------------------------------------
// prep_kernel: fused elementwise cast (x->xb) + two transpose_cast jobs.
// grid 5120 x 256: [0,4096) cast; [4096,4864) w_in T; [4864,5120) w_out T.
// ---------------------------------------------------------------------------
__device__ __forceinline__ void transpose_cast_body(
    const float* __restrict__ in, unsigned short* __restrict__ out,
    int R, int C, int bx, int by, int tid, float tile[64][65]) {
  int r0 = by * 64, c0 = bx * 64;
#pragma unroll
  for (int p = 0; p < 4; p++) {
    int i = tid + p * 256;              // 0..1023: 64 rows x 16 float4
    int ri = i >> 4, c4 = (i & 15) * 4;
    float4 v = *(const float4*)&in[(size_t)(r0 + ri) * C + c0 + c4];
    tile[ri][c4 + 0] = v.x; tile[ri][c4 + 1] = v.y;
    tile[ri][c4 + 2] = v.z; tile[ri][c4 + 3] = v.w;
  }
  __syncthreads();
#pragma unroll
  for (int p = 0; p < 8; p++) {
    int i = tid + p * 256;              // 0..2047: 64 cols x 32 row-pairs
    int ci = i >> 5, rp = (i & 31) * 2;
    ushort2 o;
    o.x = f2b(tile[rp][ci]);
    o.y = f2b(tile[rp + 1][ci]);
    *(ushort2*)&out[(size_t)(c0 + ci) * R + r0 + rp] = o;
  }
}

__global__ __launch_bounds__(256) void prep_kernel(
    const float* __restrict__ x, unsigned short* __restrict__ xb,
    const float* __restrict__ w_in, unsigned short* __restrict__ wint,
    const float* __restrict__ w_out, unsigned short* __restrict__ woutt) {
  __shared__ float tile[64][65];
  int bid = blockIdx.x, tid = threadIdx.x;
  if (bid < 4096) {
    int i = bid * 256 + tid;   // n4 = 1048576 exactly = 4096*256
    float4 v = ((const float4*)x)[i];
    ushort4 o;
    o.x = f2b(v.x); o.y = f2b(v.y); o.z = f2b(v.z); o.w = f2b(v.w);
    ((ushort4*)xb)[i] = o;
  } else if (bid < 4864) {
    int l = bid - 4096;        // 768 blocks: (48 x, 16 y)
    transpose_cast_body(w_in, wint, 1024, 3072, l % 48, l / 48, tid, tile);
  } else {
    int l = bid - 4864;        // 256 blocks: (16 x, 16 y)
    transpose_cast_body(w_out, woutt, 1024, 1024, l % 16, l / 16, tid, tile);
  }
}

// ---------------------------------------------------------------------------
// GEMM1: C[M,N] = A[M,K]*Bt[N,K]^T + bias[N], bf16 out. 128x128 tile, BK=32.
// R16 2-phase dbuf. R19 XCD swizzle: linear j = bx + 24*by; XCD = j%8
// (round-robin heuristic); XCD x0 owns logical by in [4*x0, 4*x0+4) so each
// XCD's L2 fetches only 4 A-panels (1MB) instead of the whole A matrix.
// Blocks with bx>=16 (V cols) also scatter to vt[((b*16+h)*64+d)*2048+s].
// ---------------------------------------------------------------------------
__global__ __launch_bounds__(256) void gemm_bt1(
    const unsigned short* __restrict__ A, const unsigned short* __restrict__ Bt,
    const float* __restrict__ bias, unsigned short* __restrict__ Cp,
    unsigned short* __restrict__ vtp,
    int M, int N, int K, int qcols, float qscale) {
  __shared__ __align__(16) unsigned short As[2][128 * 32];   // 2 x 8KB
  __shared__ __align__(16) unsigned short Bs[2][128 * 32];   // 2 x 8KB
  // XCD swizzle (bijective): j in [0,768), x0=j&7, s=j>>3 in [0,96),
  // yl=s/24 in [0,4), bx=s-24*yl, by=4*x0+yl.
  int j = blockIdx.x + 24 * blockIdx.y;
  int x0 = j & 7, s_ = j >> 3;
  int yl = s_ / 24;
  int bx = s_ - yl * 24;
  int by = (x0 << 2) + yl;

  int tid = threadIdx.x;
  int wave = tid >> 6, lane = tid & 63;
  int m_l = lane & 15, quad = lane >> 4;
  int wm = (wave >> 1) * 64, wn = (wave & 1) * 64;
  int row = tid >> 2, kp = (tid & 3) << 3;
  const unsigned short* ag = A + (size_t)(by * 128 + row) * K + kp;
  const unsigned short* bg = Bt + (size_t)(bx * 128 + row) * K + kp;
  f32x4 acc[4][4] = {};

  auto stage = [&](int k0, int sb) {
    gl_lds16(ag + k0, &As[sb][wave * 512]);
    gl_lds16(ag + (size_t)64 * K + k0, &As[sb][2048 + wave * 512]);
    gl_lds16(bg + k0, &Bs[sb][wave * 512]);
    gl_lds16(bg + (size_t)64 * K + k0, &Bs[sb][2048 + wave * 512]);
  };
  auto compute = [&](int sb) {
    bf16x8 af[4], bf[4];
#pragma unroll
    for (int i = 0; i < 4; i++)
      af[i] = *(const bf16x8*)&As[sb][(wm + i * 16 + m_l) * 32 + quad * 8];
#pragma unroll
    for (int jj = 0; jj < 4; jj++)
      bf[jj] = *(const bf16x8*)&Bs[sb][(wn + jj * 16 + m_l) * 32 + quad * 8];
#pragma unroll
    for (int i = 0; i < 4; i++)
#pragma unroll
      for (int jj = 0; jj < 4; jj++)
        acc[i][jj] = __builtin_amdgcn_mfma_f32_16x16x32_bf16(af[i], bf[jj], acc[i][jj], 0, 0, 0);
  };

  stage(0, 0);
  __syncthreads();
  for (int k0 = 0; k0 < K; k0 += 64) {
    if (k0 + 32 < K) stage(k0 + 32, 1);
    compute(0);
    __syncthreads();
    if (k0 + 64 < K) stage(k0 + 64, 0);
    compute(1);
    __syncthreads();
  }

  float bv[4];
#pragma unroll
  for (int jj = 0; jj < 4; jj++) bv[jj] = bias[bx * 128 + wn + jj * 16 + m_l];
  bool isV = (bx >= 16);                      // V columns: n in [2048,3072)
  int bb = (by * 128) >> 11;                  // batch index, block-uniform
  unsigned short* vbase = vtp + (size_t)bb * 16 * 64 * 2048;
#pragma unroll
  for (int i = 0; i < 4; i++) {
    int m = by * 128 + wm + i * 16 + quad * 4;
    int s = m & 2047;
#pragma unroll
    for (int jj = 0; jj < 4; jj++) {
      int n = bx * 128 + wn + jj * 16 + m_l;
      float sc = (n < qcols) ? qscale : 1.0f;
      int nv = n - 2048;                     // = h*64+d when isV
#pragma unroll
      for (int r = 0; r < 4; r++) {
        float v = (acc[i][jj][r] + bv[jj]) * sc;
        unsigned short hv = f2b(v);
        Cp[(size_t)(m + r) * N + n] = hv;
        if (isV) vbase[(size_t)nv * 2048 + s + r] = hv;
      }
    }
  }
}

// ---------------------------------------------------------------------------
// GEMM2: C[M,N] = A[M,K]*Bt[N,K]^T + bias[N], fp32 out.
// 128x128 tile, 512 thr = 8 waves (2 wm x 4 wn), each 64x32 output.
// R16 exact 2-phase structure. R19 XCD swizzle: j = bx + 8*by; XCD x0 owns
// by in [4*x0,4*x0+4) -> each XCD fetches 4 attn row-panels (1MB), not 8MB.
// ---------------------------------------------------------------------------
__global__ __launch_bounds__(512) void gemm_bt2(
    const unsigned short* __restrict__ A, const unsigned short* __restrict__ Bt,
    const float* __restrict__ bias, float* __restrict__ Cp, int M, int N, int K) {
  __shared__ __align__(16) unsigned short As[2][128 * 32];
  __shared__ __align__(16) unsigned short Bs[2][128 * 32];
  // XCD swizzle (bijective): j in [0,256), x0=j&7, s=j>>3 in [0,32),
  // yl=s>>3 in [0,4), bx=s&7, by=4*x0+yl.
  int j = blockIdx.x + 8 * blockIdx.y;
  int x0 = j & 7, s_ = j >> 3;
  int yl = s_ >> 3, bx = s_ & 7;
  int by = (x0 << 2) + yl;

  int tid = threadIdx.x;
  int wave = tid >> 6, lane = tid & 63;
  int m_l = lane & 15, quad = lane >> 4;
  int wm = (wave >> 2) * 64, wn = (wave & 3) * 32;
  int row = tid >> 2, kp = (tid & 3) << 3;    // 128 rows x 4 chunks of 16B
  const unsigned short* ag = A + (size_t)(by * 128 + row) * K + kp;
  const unsigned short* bg = Bt + (size_t)(bx * 128 + row) * K + kp;
  f32x4 acc[4][2] = {};

  auto stage = [&](int k0, int sb) {
    gl_lds16(ag + k0, &As[sb][wave * 512]);
    gl_lds16(bg + k0, &Bs[sb][wave * 512]);
  };
  auto compute = [&](int sb) {
    bf16x8 af[4], bf[2];
#pragma unroll
    for (int i = 0; i < 4; i++)
      af[i] = *(const bf16x8*)&As[sb][(wm + i * 16 + m_l) * 32 + quad * 8];
#pragma unroll
    for (int jj = 0; jj < 2; jj++)
      bf[jj] = *(const bf16x8*)&Bs[sb][(wn + jj * 16 + m_l) * 32 + quad * 8];
#pragma unroll
    for (int i = 0; i < 4; i++)
#pragma unroll
      for (int jj = 0; jj < 2; jj++)
        acc[i][jj] = __builtin_amdgcn_mfma_f32_16x16x32_bf16(af[i], bf[jj], acc[i][jj], 0, 0, 0);
  };

  stage(0, 0);
  __syncthreads();
  for (int k0 = 0; k0 < K; k0 += 64) {
    if (k0 + 32 < K) stage(k0 + 32, 1);
    compute(0);
    __syncthreads();
    if (k0 + 64 < K) stage(k0 + 64, 0);
    compute(1);
    __syncthreads();
  }

  float bv[2];
#pragma unroll
  for (int jj = 0; jj < 2; jj++) bv[jj] = bias[bx * 128 + wn + jj * 16 + m_l];
#pragma unroll
  for (int i = 0; i < 4; i++) {
    int m = by * 128 + wm + i * 16 + quad * 4;
#pragma unroll
    for (int jj = 0; jj < 2; jj++) {
      int n = bx * 128 + wn + jj * 16 + m_l;
#pragma unroll
      for (int r = 0; r < 4; r++)
        Cp[(size_t)(m + r) * N + n] = acc[i][jj][r] + bv[jj];
    }
  }
}

// ---------------------------------------------------------------------------
// Flash attention, 32x32x16 MFMA (fragments HW-verified R10/R11).
// 512 threads = 8 waves. Waves w and w+4 own q-group (w&3); wave w handles
// keys [kt,kt+64), wave w+4 keys [kt+64,kt+128) per 128-key round (16 rounds).
// Grid 512 -> 2 blocks/CU, 16 waves/CU (80KB LDS = exactly 2 blocks/CU).
// Double-buffered K/V: stage(next) || compute(cur), ONE __syncthreads/round.
// R19 XCD swizzle: the 16 q-tile blocks sharing one (h,b)'s K/V map to one
// XCD (4 groups x 512KB = 2MB < 4MB L2) -> K/V L2-resident after first touch.
// End: waves 4-7 publish partials; 0-3 combine.
// ---------------------------------------------------------------------------
__global__ __launch_bounds__(512, 4) void attn_kernel(
    const unsigned short* __restrict__ qkv, const unsigned short* __restrict__ vt,
    unsigned short* __restrict__ aout) {
  // 80 KB: Qs[128][64] | Ks[2][128][64] | Vts[2][64][128]  (shorts)
  __shared__ __align__(16) unsigned short smem[40960];
  unsigned short* Qs  = smem;           // 8192 shorts
  unsigned short* Ks0 = smem + 8192;    // 8192
  unsigned short* Ks1 = smem + 16384;   // 8192
  unsigned short* Vt0 = smem + 24576;   // 8192
  unsigned short* Vt1 = smem + 32768;   // 8192

  // XCD swizzle (bijective): bid in [0,512); XCD = bid&7 (round-robin
  // heuristic). group g = (bid&7) + 8*(bid>>7) in [0,32); qt = (bid>>3)&15.
  int bid = blockIdx.x;
  int g = (bid & 7) + ((bid >> 7) << 3);
  int qt = (bid >> 3) & 15;
  int h = g & 15, b = g >> 4;
  int tid = threadIdx.x, wave = tid >> 6, lane = tid & 63;
  int l31 = lane & 31, hi = lane >> 5, l7 = lane & 7;
  int w03 = wave & 3;                 // q-group
  int koff = (wave >> 2) * 64;        // key half within the 128-key round
  int q0 = qt * 128;
  const unsigned short* qb = qkv + (size_t)b * 2048 * 3072 + h * 64;
  const unsigned short* kb = qb + 1024;
  const unsigned short* vtb = vt + (size_t)(b * 16 + h) * 64 * 2048;

  // K/Q staging: 512 threads cover 64 rows x 8 chunks; source chunk
  // (tid&7)^(row&7) so LDS[row][slot c] holds global chunk c^(row&7).
  int srow = tid >> 3;                      // 0..63
  int sd0 = ((tid & 7) ^ (srow & 7)) * 8;
  // V staging: 512 threads cover 32 d-rows x 16 chunks; slot s holds global
  // chunk (s&8) | ((s&7)^(d&7)).
  int dv = tid >> 4;                        // 0..31
  int sv = tid & 15;
  int gv = (sv & 8) | ((sv & 7) ^ (dv & 7));

  auto stageKV = [&](unsigned short* Kb, unsigned short* Vb, int kt) {
    gl_lds16(kb + (size_t)(kt + srow) * 3072 + sd0, Kb + wave * 512);
    gl_lds16(kb + (size_t)(kt + 64 + srow) * 3072 + sd0, Kb + 4096 + wave * 512);
    gl_lds16(vtb + (size_t)dv * 2048 + kt + gv * 8, Vb + wave * 512);
    gl_lds16(vtb + (size_t)(32 + dv) * 2048 + kt + gv * 8, Vb + 4096 + wave * 512);
  };

  // stage Q[128][64] (2 rounds of 64 rows) + first K/V buffer
#pragma unroll
  for (int p = 0; p < 2; p++)
    gl_lds16(qb + (size_t)(q0 + p * 64 + srow) * 3072 + sd0, Qs + p * 4096 + wave * 512);
  stageKV(Ks0, Vt0, 0);
  __syncthreads();

  // Q B-frags (hoisted): q = w03*32 + l31; k-slice ks: chunk 2*ks+hi
  bf16x8 qf[4];
  int qrow = (w03 * 32 + l31) * 64;
#pragma unroll
  for (int ks = 0; ks < 4; ks++)
    qf[ks] = *(const bf16x8*)&Qs[qrow + ((2 * ks + hi) ^ l7) * 8];

  union { s16x8 s; bf16x8 v; } onesu;
  onesu.s = (s16x8){0x3F80, 0x3F80, 0x3F80, 0x3F80, 0x3F80, 0x3F80, 0x3F80, 0x3F80};

  f32x16 oacc[2] = {};   // O^T partial accumulators, dtile = d/32
  f32x16 lacc = {};      // lp partial via ones-MFMA (all regs = column sum)
  f32x16 z16 = {};       // hoisted zero C-operand

  auto computeKV = [&](const unsigned short* Kb, const unsigned short* Vb) {
#pragma unroll
    for (int tt = 0; tt < 2; tt++) {
      // S^T[key 32][q 32] for this wave's keytile (koff + tt*32)
      bf16x8 kf0 = *(const bf16x8*)&Kb[(koff + tt * 32 + l31) * 64 + ((2 * 0 + hi) ^ l7) * 8];
      f32x16 sacc = __builtin_amdgcn_mfma_f32_32x32x16_bf16(kf0, qf[0], z16, 0, 0, 0);
#pragma unroll
      for (int ks = 1; ks < 4; ks++) {
        bf16x8 kf = *(const bf16x8*)&Kb[(koff + tt * 32 + l31) * 64 + ((2 * ks + hi) ^ l7) * 8];
        sacc = __builtin_amdgcn_mfma_f32_32x32x16_bf16(kf, qf[ks], sacc, 0, 0, 0);
      }
      float pv[16];
#pragma unroll
      for (int i = 0; i < 16; i++) pv[i] = __builtin_exp2f(sacc[i]);
#pragma unroll
      for (int g2 = 0; g2 < 2; g2++) {
        // own regs 8g..8g+3 -> rows 16g+4hi+{0..3}; 8g+4..8g+7 -> 16g+8+4hi+{0..3}
        unsigned a0 = cvt_pk_bf16(pv[8 * g2 + 0], pv[8 * g2 + 1]);
        unsigned a1 = cvt_pk_bf16(pv[8 * g2 + 2], pv[8 * g2 + 3]);
        unsigned b0 = cvt_pk_bf16(pv[8 * g2 + 4], pv[8 * g2 + 5]);
        unsigned b1 = cvt_pk_bf16(pv[8 * g2 + 6], pv[8 * g2 + 7]);
        permlane32_swap(a0, b0);  // a0={keys 16g+8hi+0,1}, b0={keys 16g+8hi+4,5}
        permlane32_swap(a1, b1);  // a1={keys 16g+8hi+2,3}, b1={keys 16g+8hi+6,7}
        union { unsigned u[4]; bf16x8 v; } pf;
        pf.u[0] = a0; pf.u[1] = a1; pf.u[2] = b0; pf.u[3] = b1;
        lacc = __builtin_amdgcn_mfma_f32_32x32x16_bf16(onesu.v, pf.v, lacc, 0, 0, 0);
        int kc = tt * 2 + g2;     // 16-key slice within this wave's 64-key half
#pragma unroll
        for (int dt = 0; dt < 2; dt++) {
          bf16x8 vf = *(const bf16x8*)&Vb[(dt * 32 + l31) * 128 +
                                          ((koff >> 3) | ((kc * 2 + hi) ^ l7)) * 8];
          oacc[dt] = __builtin_amdgcn_mfma_f32_32x32x16_bf16(vf, pf.v, oacc[dt], 0, 0, 0);
        }
      }
    }
  };

  // 16 rounds of 128 keys, unrolled x2 for static buffer selection.
  for (int kt = 0; kt < 2048; kt += 256) {
    stageKV(Ks1, Vt1, kt + 128);          // async prefetch next round
    __builtin_amdgcn_s_setprio(1);
    computeKV(Ks0, Vt0);
    __builtin_amdgcn_s_setprio(0);
    __syncthreads();                       // drains prefetch (aged a full phase)
    if (kt + 256 < 2048) stageKV(Ks0, Vt0, kt + 256);
    __builtin_amdgcn_s_setprio(1);
    computeKV(Ks1, Vt1);
    __builtin_amdgcn_s_setprio(0);
    __syncthreads();
  }

  // pair-combine: waves 4-7 publish partials; waves 0-3 add + store.
  float* red = (float*)smem;   // scratch; layout: 4 groups x 2048 f32 + lp
  float* lpred = red + 8192;
  if (wave >= 4) {
    float* basep = red + w03 * 2048;
#pragma unroll
    for (int dt = 0; dt < 2; dt++)
#pragma unroll
      for (int r = 0; r < 4; r++) {
        f32x4 c4 = {oacc[dt][4 * r + 0], oacc[dt][4 * r + 1],
                    oacc[dt][4 * r + 2], oacc[dt][4 * r + 3]};
        ((f32x4*)basep)[lane * 8 + ((dt * 4 + r) ^ (lane & 7))] = c4;
      }
    lpred[w03 * 64 + lane] = lacc[0];
  }
  __syncthreads();
  if (wave < 4) {
    float* basep = red + w03 * 2048;
#pragma unroll
    for (int dt = 0; dt < 2; dt++)
#pragma unroll
      for (int r = 0; r < 4; r++) {
        f32x4 c4 = ((f32x4*)basep)[lane * 8 + ((dt * 4 + r) ^ (lane & 7))];
        oacc[dt][4 * r + 0] += c4[0];
        oacc[dt][4 * r + 1] += c4[1];
        oacc[dt][4 * r + 2] += c4[2];
        oacc[dt][4 * r + 3] += c4[3];
      }
    float rl = 1.0f / (lacc[0] + lpred[w03 * 64 + lane]);

    // epilogue: O^T frag col=q=l31, row d = 32*dt + 8*(reg>>2) + 4*hi + (reg&3)
    unsigned short* ob = aout + (size_t)(b * 2048 + q0 + w03 * 32 + l31) * 1024 + h * 64;
#pragma unroll
    for (int dt = 0; dt < 2; dt++)
#pragma unroll
      for (int rq = 0; rq < 4; rq++) {
        union { uint2 u; ushort4 w; } pk;
        pk.u.x = cvt_pk_bf16(oacc[dt][4 * rq + 0] * rl, oacc[dt][4 * rq + 1] * rl);
        pk.u.y = cvt_pk_bf16(oacc[dt][4 * rq + 2] * rl, oacc[dt][4 * rq + 3] * rl);
        *(ushort4*)&ob[dt * 32 + rq * 8 + hi * 4] = pk.w;
      }
  }
}

// ---------------------------------------------------------------------------
extern "C" void kernel_launch(void* const* d_in, const int* in_sizes, int n_in,
                              void* d_out, int out_size, void* d_ws, size_t ws_size,
                              hipStream_t stream) {
  (void)in_sizes; (void)n_in; (void)out_size; (void)ws_size;
  const float* x     = (const float*)d_in[0];
  const float* w_in  = (const float*)d_in[1];
  const float* b_in  = (const float*)d_in[2];
  const float* w_out = (const float*)d_in[3];
  const float* b_out = (const float*)d_in[4];
  char* ws = (char*)d_ws;
  unsigned short* xb    = (unsigned short*)(ws + 0);          //  8 MB
  unsigned short* wint  = (unsigned short*)(ws + 8388608);    //  6 MB
  unsigned short* woutt = (unsigned short*)(ws + 14680064);   //  2 MB
  unsigned short* qkv   = (unsigned short*)(ws + 16777216);   // 24 MB
  unsigned short* vt    = (unsigned short*)(ws + 41943040);   //  8 MB
  unsigned short* attn  = (unsigned short*)(ws + 50331648);   //  8 MB
  float* out = (float*)d_out;

  const float QSCALE = 0.125f * 1.44269504088896f;  // fold 1/sqrt(64) * log2(e)

  prep_kernel<<<5120, 256, 0, stream>>>(x, xb, w_in, wint, w_out, woutt);
  gemm_bt1<<<dim3(24, 32), 256, 0, stream>>>(xb, wint, b_in, qkv, vt,
                                             4096, 3072, 1024, 1024, QSCALE);
  attn_kernel<<<512, 512, 0, stream>>>(qkv, vt, attn);
  gemm_bt2<<<dim3(8, 32), 512, 0, stream>>>(attn, woutt, b_out, out, 4096, 1024, 1024);
}

// Round 12
// 186.466 us; speedup vs baseline: 1.0609x; 1.0492x over previous
//
#include <hip/hip_runtime.h>

// ---------------------------------------------------------------------------
// MultiHeadAttention: B=2, S=2048, E=1024, H=16, D=64
//   1. prep_kernel (fused): cast x->bf16; transpose+cast w_in, w_out
//      (float4 loads, ushort2 stores).
//   2. GEMM1: qkv = x @ w_in + b_in (bf16; Q pre-scaled by 0.125*log2e);
//      V-transpose fused into epilogue; R16 2-phase dbuf; R19 XCD swizzle.
//   3. flash attention — 32x32x16 MFMA, wave-pair key-split, dbuf K/V,
//      setprio, hoisted zero C-operand; R19 XCD swizzle (FETCH 70->12 MB,
//      K/V L2-resident per XCD).
//   4. GEMM2: out = attn @ w_out + b_out. 128x128 tile, 512 thr.
//      R20 static 4-buffer distance-2 pipeline; R21 FIX: launch grid was
//      dim3(16,32) (512 blocks) against a 256-block swizzle -> OOB crash.
//      Correct grid is dim3(8,32).
// ---------------------------------------------------------------------------

typedef __bf16 bf16x8 __attribute__((ext_vector_type(8)));
typedef float  f32x4  __attribute__((ext_vector_type(4)));
typedef float  f32x16 __attribute__((ext_vector_type(16)));
typedef short  s16x8  __attribute__((ext_vector_type(8)));

__device__ __forceinline__ unsigned short f2b(float f) {
  unsigned u = __float_as_uint(f);
  unsigned r = u + 0x7fffu + ((u >> 16) & 1u);   // round-to-nearest-even
  return (unsigned short)(r >> 16);
}

// gfx950 HW packed fp32->bf16 convert (RNE): low16=cvt(a), high16=cvt(b).
__device__ __forceinline__ unsigned cvt_pk_bf16(float a, float b) {
#if defined(__HIP_DEVICE_COMPILE__)
  unsigned r;
  asm("v_cvt_pk_bf16_f32 %0, %1, %2" : "=v"(r) : "v"(a), "v"(b));
  return r;
#else
  return (unsigned)f2b(a) | ((unsigned)f2b(b) << 16);
#endif
}

// v_permlane32_swap_b32 a, b:  a' = {a_lo, b_lo}, b' = {a_hi, b_hi}
__device__ __forceinline__ void permlane32_swap(unsigned& a, unsigned& b) {
#if defined(__HIP_DEVICE_COMPILE__)
  asm("v_permlane32_swap_b32 %0, %1" : "+v"(a), "+v"(b));
#endif
}

// async global->LDS, 16 bytes per lane; HW writes lane i at lds + i*16.
__device__ __forceinline__ void gl_lds16(const void* g, void* l) {
  __builtin_amdgcn_global_load_lds(
      (__attribute__((address_space(1))) void*)g,
      (__attribute__((address_space(3))) void*)l, 16, 0, 0);
}

#define VMCNT(n) asm volatile("s_waitcnt vmcnt(" #n ")" ::: "memory")

// ---------------------------------------------------------------------------
// prep_kernel: fused elementwise cast (x->xb) + two transpose_cast jobs.
// grid 5120 x 256: [0,4096) cast; [4096,4864) w_in T; [4864,5120) w_out T.
// ---------------------------------------------------------------------------
__device__ __forceinline__ void transpose_cast_body(
    const float* __restrict__ in, unsigned short* __restrict__ out,
    int R, int C, int bx, int by, int tid, float tile[64][65]) {
  int r0 = by * 64, c0 = bx * 64;
#pragma unroll
  for (int p = 0; p < 4; p++) {
    int i = tid + p * 256;              // 0..1023: 64 rows x 16 float4
    int ri = i >> 4, c4 = (i & 15) * 4;
    float4 v = *(const float4*)&in[(size_t)(r0 + ri) * C + c0 + c4];
    tile[ri][c4 + 0] = v.x; tile[ri][c4 + 1] = v.y;
    tile[ri][c4 + 2] = v.z; tile[ri][c4 + 3] = v.w;
  }
  __syncthreads();
#pragma unroll
  for (int p = 0; p < 8; p++) {
    int i = tid + p * 256;              // 0..2047: 64 cols x 32 row-pairs
    int ci = i >> 5, rp = (i & 31) * 2;
    ushort2 o;
    o.x = f2b(tile[rp][ci]);
    o.y = f2b(tile[rp + 1][ci]);
    *(ushort2*)&out[(size_t)(c0 + ci) * R + r0 + rp] = o;
  }
}

__global__ __launch_bounds__(256) void prep_kernel(
    const float* __restrict__ x, unsigned short* __restrict__ xb,
    const float* __restrict__ w_in, unsigned short* __restrict__ wint,
    const float* __restrict__ w_out, unsigned short* __restrict__ woutt) {
  __shared__ float tile[64][65];
  int bid = blockIdx.x, tid = threadIdx.x;
  if (bid < 4096) {
    int i = bid * 256 + tid;   // n4 = 1048576 exactly = 4096*256
    float4 v = ((const float4*)x)[i];
    ushort4 o;
    o.x = f2b(v.x); o.y = f2b(v.y); o.z = f2b(v.z); o.w = f2b(v.w);
    ((ushort4*)xb)[i] = o;
  } else if (bid < 4864) {
    int l = bid - 4096;        // 768 blocks: (48 x, 16 y)
    transpose_cast_body(w_in, wint, 1024, 3072, l % 48, l / 48, tid, tile);
  } else {
    int l = bid - 4864;        // 256 blocks: (16 x, 16 y)
    transpose_cast_body(w_out, woutt, 1024, 1024, l % 16, l / 16, tid, tile);
  }
}

// ---------------------------------------------------------------------------
// GEMM1: C[M,N] = A[M,K]*Bt[N,K]^T + bias[N], bf16 out. 128x128 tile, BK=32.
// R16 2-phase dbuf + R19 XCD swizzle (each XCD owns 4 row-panels).
// Blocks with bx>=16 (V cols) also scatter to vt[((b*16+h)*64+d)*2048+s].
// ---------------------------------------------------------------------------
__global__ __launch_bounds__(256) void gemm_bt1(
    const unsigned short* __restrict__ A, const unsigned short* __restrict__ Bt,
    const float* __restrict__ bias, unsigned short* __restrict__ Cp,
    unsigned short* __restrict__ vtp,
    int M, int N, int K, int qcols, float qscale) {
  __shared__ __align__(16) unsigned short As[2][128 * 32];   // 2 x 8KB
  __shared__ __align__(16) unsigned short Bs[2][128 * 32];   // 2 x 8KB
  // XCD swizzle (bijective): j in [0,768), x0=j&7, s=j>>3 in [0,96),
  // yl=s/24 in [0,4), bx=s-24*yl, by=4*x0+yl.
  int j = blockIdx.x + 24 * blockIdx.y;
  int x0 = j & 7, s_ = j >> 3;
  int yl = s_ / 24;
  int bx = s_ - yl * 24;
  int by = (x0 << 2) + yl;

  int tid = threadIdx.x;
  int wave = tid >> 6, lane = tid & 63;
  int m_l = lane & 15, quad = lane >> 4;
  int wm = (wave >> 1) * 64, wn = (wave & 1) * 64;
  int row = tid >> 2, kp = (tid & 3) << 3;
  const unsigned short* ag = A + (size_t)(by * 128 + row) * K + kp;
  const unsigned short* bg = Bt + (size_t)(bx * 128 + row) * K + kp;
  f32x4 acc[4][4] = {};

  auto stage = [&](int k0, int sb) {
    gl_lds16(ag + k0, &As[sb][wave * 512]);
    gl_lds16(ag + (size_t)64 * K + k0, &As[sb][2048 + wave * 512]);
    gl_lds16(bg + k0, &Bs[sb][wave * 512]);
    gl_lds16(bg + (size_t)64 * K + k0, &Bs[sb][2048 + wave * 512]);
  };
  auto compute = [&](int sb) {
    bf16x8 af[4], bf[4];
#pragma unroll
    for (int i = 0; i < 4; i++)
      af[i] = *(const bf16x8*)&As[sb][(wm + i * 16 + m_l) * 32 + quad * 8];
#pragma unroll
    for (int jj = 0; jj < 4; jj++)
      bf[jj] = *(const bf16x8*)&Bs[sb][(wn + jj * 16 + m_l) * 32 + quad * 8];
#pragma unroll
    for (int i = 0; i < 4; i++)
#pragma unroll
      for (int jj = 0; jj < 4; jj++)
        acc[i][jj] = __builtin_amdgcn_mfma_f32_16x16x32_bf16(af[i], bf[jj], acc[i][jj], 0, 0, 0);
  };

  stage(0, 0);
  __syncthreads();
  for (int k0 = 0; k0 < K; k0 += 64) {
    if (k0 + 32 < K) stage(k0 + 32, 1);
    compute(0);
    __syncthreads();
    if (k0 + 64 < K) stage(k0 + 64, 0);
    compute(1);
    __syncthreads();
  }

  float bv[4];
#pragma unroll
  for (int jj = 0; jj < 4; jj++) bv[jj] = bias[bx * 128 + wn + jj * 16 + m_l];
  bool isV = (bx >= 16);                      // V columns: n in [2048,3072)
  int bb = (by * 128) >> 11;                  // batch index, block-uniform
  unsigned short* vbase = vtp + (size_t)bb * 16 * 64 * 2048;
#pragma unroll
  for (int i = 0; i < 4; i++) {
    int m = by * 128 + wm + i * 16 + quad * 4;
    int s = m & 2047;
#pragma unroll
    for (int jj = 0; jj < 4; jj++) {
      int n = bx * 128 + wn + jj * 16 + m_l;
      float sc = (n < qcols) ? qscale : 1.0f;
      int nv = n - 2048;                     // = h*64+d when isV
#pragma unroll
      for (int r = 0; r < 4; r++) {
        float v = (acc[i][jj][r] + bv[jj]) * sc;
        unsigned short hv = f2b(v);
        Cp[(size_t)(m + r) * N + n] = hv;
        if (isV) vbase[(size_t)nv * 2048 + s + r] = hv;
      }
    }
  }
}

// ---------------------------------------------------------------------------
// GEMM2: C[M,N] = A[M,K]*Bt[N,K]^T + bias[N], fp32 out.
// 128x128 tile, 512 thr = 8 waves (2 wm x 4 wn), each 64x32 output.
// Static 4-buffer prefetch-distance-2, ONE barrier/k-step:
//   per step i: stage(step i+2 -> buf (i+2)&3); vmcnt(4); s_barrier;
//               compute(buf i&3)
// WAR-safe: buf (i+2)&3 was read at compute(i-2); barrier(i+1 boundary)
// orders the stage after all waves' reads. vmcnt(4) leaves only the 2
// newest stages outstanding -> compute's buffer landed.
// Grid MUST be dim3(8,32) = 256 blocks (swizzle domain) = 1 block/CU.
// ---------------------------------------------------------------------------
__global__ __launch_bounds__(512) void gemm_bt2(
    const unsigned short* __restrict__ A, const unsigned short* __restrict__ Bt,
    const float* __restrict__ bias, float* __restrict__ Cp, int M, int N, int K) {
  __shared__ __align__(16) unsigned short As[4][128 * 32];   // 4 x 8KB
  __shared__ __align__(16) unsigned short Bs[4][128 * 32];   // 4 x 8KB
  // XCD swizzle (bijective): j in [0,256), x0=j&7, s=j>>3 in [0,32),
  // yl=s>>3 in [0,4), bx=s&7, by=4*x0+yl.
  int j = blockIdx.x + 8 * blockIdx.y;
  int x0 = j & 7, s_ = j >> 3;
  int yl = s_ >> 3, bx = s_ & 7;
  int by = (x0 << 2) + yl;

  int tid = threadIdx.x;
  int wave = tid >> 6, lane = tid & 63;
  int m_l = lane & 15, quad = lane >> 4;
  int wm = (wave >> 2) * 64, wn = (wave & 3) * 32;
  int row = tid >> 2, kp = (tid & 3) << 3;    // 128 rows x 4 chunks of 16B
  const unsigned short* ag = A + (size_t)(by * 128 + row) * K + kp;
  const unsigned short* bg = Bt + (size_t)(bx * 128 + row) * K + kp;
  f32x4 acc[4][2] = {};

  auto stage = [&](int k0, int sb) {     // 2 loads/wave
    gl_lds16(ag + k0, &As[sb][wave * 512]);
    gl_lds16(bg + k0, &Bs[sb][wave * 512]);
  };
  auto compute = [&](int sb) {
    bf16x8 af[4], bf[2];
#pragma unroll
    for (int i = 0; i < 4; i++)
      af[i] = *(const bf16x8*)&As[sb][(wm + i * 16 + m_l) * 32 + quad * 8];
#pragma unroll
    for (int jj = 0; jj < 2; jj++)
      bf[jj] = *(const bf16x8*)&Bs[sb][(wn + jj * 16 + m_l) * 32 + quad * 8];
#pragma unroll
    for (int i = 0; i < 4; i++)
#pragma unroll
      for (int jj = 0; jj < 2; jj++)
        acc[i][jj] = __builtin_amdgcn_mfma_f32_16x16x32_bf16(af[i], bf[jj], acc[i][jj], 0, 0, 0);
  };

  // K = 1024 -> 32 k-steps of 32. Static x4-unrolled distance-2 pipeline.
  stage(0, 0);        // step 0
  stage(32, 1);       // step 1
  // groups g=0..6: computes steps 4g..4g+3, stages steps 4g+2..4g+5.
  for (int g = 0; g < 7; ++g) {
    int k = g << 7;   // g*128
    stage(k + 64, 2);  VMCNT(4); __builtin_amdgcn_s_barrier(); compute(0);
    stage(k + 96, 3);  VMCNT(4); __builtin_amdgcn_s_barrier(); compute(1);
    stage(k + 128, 0); VMCNT(4); __builtin_amdgcn_s_barrier(); compute(2);
    stage(k + 160, 1); VMCNT(4); __builtin_amdgcn_s_barrier(); compute(3);
  }
  // tail: steps 28..31 (staged: 28->b0, 29->b1 by g=6; stage 30->b2, 31->b3)
  stage(960, 2); VMCNT(4); __builtin_amdgcn_s_barrier(); compute(0);
  stage(992, 3); VMCNT(4); __builtin_amdgcn_s_barrier(); compute(1);
  VMCNT(2);      __builtin_amdgcn_s_barrier(); compute(2);
  VMCNT(0);      __builtin_amdgcn_s_barrier(); compute(3);

  float bv[2];
#pragma unroll
  for (int jj = 0; jj < 2; jj++) bv[jj] = bias[bx * 128 + wn + jj * 16 + m_l];
#pragma unroll
  for (int i = 0; i < 4; i++) {
    int m = by * 128 + wm + i * 16 + quad * 4;
#pragma unroll
    for (int jj = 0; jj < 2; jj++) {
      int n = bx * 128 + wn + jj * 16 + m_l;
#pragma unroll
      for (int r = 0; r < 4; r++)
        Cp[(size_t)(m + r) * N + n] = acc[i][jj][r] + bv[jj];
    }
  }
}

// ---------------------------------------------------------------------------
// Flash attention, 32x32x16 MFMA (fragments HW-verified R10/R11).
// 512 threads = 8 waves. Waves w and w+4 own q-group (w&3); wave w handles
// keys [kt,kt+64), wave w+4 keys [kt+64,kt+128) per 128-key round (16 rounds).
// Grid 512 -> 2 blocks/CU, 16 waves/CU (80KB LDS = exactly 2 blocks/CU).
// Double-buffered K/V: stage(next) || compute(cur), ONE __syncthreads/round.
// R19 XCD swizzle: 16 q-tile blocks sharing one (h,b)'s K/V on one XCD ->
// K/V L2-resident (measured FETCH 70 -> 12 MB).
// End: waves 4-7 publish partials; 0-3 combine.
// ---------------------------------------------------------------------------
__global__ __launch_bounds__(512, 4) void attn_kernel(
    const unsigned short* __restrict__ qkv, const unsigned short* __restrict__ vt,
    unsigned short* __restrict__ aout) {
  // 80 KB: Qs[128][64] | Ks[2][128][64] | Vts[2][64][128]  (shorts)
  __shared__ __align__(16) unsigned short smem[40960];
  unsigned short* Qs  = smem;           // 8192 shorts
  unsigned short* Ks0 = smem + 8192;    // 8192
  unsigned short* Ks1 = smem + 16384;   // 8192
  unsigned short* Vt0 = smem + 24576;   // 8192
  unsigned short* Vt1 = smem + 32768;   // 8192

  // XCD swizzle (bijective): bid in [0,512); XCD = bid&7 (round-robin
  // heuristic). group g = (bid&7) + 8*(bid>>7) in [0,32); qt = (bid>>3)&15.
  int bid = blockIdx.x;
  int g = (bid & 7) + ((bid >> 7) << 3);
  int qt = (bid >> 3) & 15;
  int h = g & 15, b = g >> 4;
  int tid = threadIdx.x, wave = tid >> 6, lane = tid & 63;
  int l31 = lane & 31, hi = lane >> 5, l7 = lane & 7;
  int w03 = wave & 3;                 // q-group
  int koff = (wave >> 2) * 64;        // key half within the 128-key round
  int q0 = qt * 128;
  const unsigned short* qb = qkv + (size_t)b * 2048 * 3072 + h * 64;
  const unsigned short* kb = qb + 1024;
  const unsigned short* vtb = vt + (size_t)(b * 16 + h) * 64 * 2048;

  // K/Q staging: 512 threads cover 64 rows x 8 chunks; source chunk
  // (tid&7)^(row&7) so LDS[row][slot c] holds global chunk c^(row&7).
  int srow = tid >> 3;                      // 0..63
  int sd0 = ((tid & 7) ^ (srow & 7)) * 8;
  // V staging: 512 threads cover 32 d-rows x 16 chunks; slot s holds global
  // chunk (s&8) | ((s&7)^(d&7)).
  int dv = tid >> 4;                        // 0..31
  int sv = tid & 15;
  int gv = (sv & 8) | ((sv & 7) ^ (dv & 7));

  auto stageKV = [&](unsigned short* Kb, unsigned short* Vb, int kt) {
    gl_lds16(kb + (size_t)(kt + srow) * 3072 + sd0, Kb + wave * 512);
    gl_lds16(kb + (size_t)(kt + 64 + srow) * 3072 + sd0, Kb + 4096 + wave * 512);
    gl_lds16(vtb + (size_t)dv * 2048 + kt + gv * 8, Vb + wave * 512);
    gl_lds16(vtb + (size_t)(32 + dv) * 2048 + kt + gv * 8, Vb + 4096 + wave * 512);
  };

  // stage Q[128][64] (2 rounds of 64 rows) + first K/V buffer
#pragma unroll
  for (int p = 0; p < 2; p++)
    gl_lds16(qb + (size_t)(q0 + p * 64 + srow) * 3072 + sd0, Qs + p * 4096 + wave * 512);
  stageKV(Ks0, Vt0, 0);
  __syncthreads();

  // Q B-frags (hoisted): q = w03*32 + l31; k-slice ks: chunk 2*ks+hi
  bf16x8 qf[4];
  int qrow = (w03 * 32 + l31) * 64;
#pragma unroll
  for (int ks = 0; ks < 4; ks++)
    qf[ks] = *(const bf16x8*)&Qs[qrow + ((2 * ks + hi) ^ l7) * 8];

  union { s16x8 s; bf16x8 v; } onesu;
  onesu.s = (s16x8){0x3F80, 0x3F80, 0x3F80, 0x3F80, 0x3F80, 0x3F80, 0x3F80, 0x3F80};

  f32x16 oacc[2] = {};   // O^T partial accumulators, dtile = d/32
  f32x16 lacc = {};      // lp partial via ones-MFMA (all regs = column sum)
  f32x16 z16 = {};       // hoisted zero C-operand

  auto computeKV = [&](const unsigned short* Kb, const unsigned short* Vb) {
#pragma unroll
    for (int tt = 0; tt < 2; tt++) {
      // S^T[key 32][q 32] for this wave's keytile (koff + tt*32)
      bf16x8 kf0 = *(const bf16x8*)&Kb[(koff + tt * 32 + l31) * 64 + ((2 * 0 + hi) ^ l7) * 8];
      f32x16 sacc = __builtin_amdgcn_mfma_f32_32x32x16_bf16(kf0, qf[0], z16, 0, 0, 0);
#pragma unroll
      for (int ks = 1; ks < 4; ks++) {
        bf16x8 kf = *(const bf16x8*)&Kb[(koff + tt * 32 + l31) * 64 + ((2 * ks + hi) ^ l7) * 8];
        sacc = __builtin_amdgcn_mfma_f32_32x32x16_bf16(kf, qf[ks], sacc, 0, 0, 0);
      }
      float pv[16];
#pragma unroll
      for (int i = 0; i < 16; i++) pv[i] = __builtin_exp2f(sacc[i]);
#pragma unroll
      for (int g2 = 0; g2 < 2; g2++) {
        // own regs 8g..8g+3 -> rows 16g+4hi+{0..3}; 8g+4..8g+7 -> 16g+8+4hi+{0..3}
        unsigned a0 = cvt_pk_bf16(pv[8 * g2 + 0], pv[8 * g2 + 1]);
        unsigned a1 = cvt_pk_bf16(pv[8 * g2 + 2], pv[8 * g2 + 3]);
        unsigned b0 = cvt_pk_bf16(pv[8 * g2 + 4], pv[8 * g2 + 5]);
        unsigned b1 = cvt_pk_bf16(pv[8 * g2 + 6], pv[8 * g2 + 7]);
        permlane32_swap(a0, b0);  // a0={keys 16g+8hi+0,1}, b0={keys 16g+8hi+4,5}
        permlane32_swap(a1, b1);  // a1={keys 16g+8hi+2,3}, b1={keys 16g+8hi+6,7}
        union { unsigned u[4]; bf16x8 v; } pf;
        pf.u[0] = a0; pf.u[1] = a1; pf.u[2] = b0; pf.u[3] = b1;
        lacc = __builtin_amdgcn_mfma_f32_32x32x16_bf16(onesu.v, pf.v, lacc, 0, 0, 0);
        int kc = tt * 2 + g2;     // 16-key slice within this wave's 64-key half
#pragma unroll
        for (int dt = 0; dt < 2; dt++) {
          bf16x8 vf = *(const bf16x8*)&Vb[(dt * 32 + l31) * 128 +
                                          ((koff >> 3) | ((kc * 2 + hi) ^ l7)) * 8];
          oacc[dt] = __builtin_amdgcn_mfma_f32_32x32x16_bf16(vf, pf.v, oacc[dt], 0, 0, 0);
        }
      }
    }
  };

  // 16 rounds of 128 keys, unrolled x2 for static buffer selection.
  for (int kt = 0; kt < 2048; kt += 256) {
    stageKV(Ks1, Vt1, kt + 128);          // async prefetch next round
    __builtin_amdgcn_s_setprio(1);
    computeKV(Ks0, Vt0);
    __builtin_amdgcn_s_setprio(0);
    __syncthreads();                       // drains prefetch (aged a full phase)
    if (kt + 256 < 2048) stageKV(Ks0, Vt0, kt + 256);
    __builtin_amdgcn_s_setprio(1);
    computeKV(Ks1, Vt1);
    __builtin_amdgcn_s_setprio(0);
    __syncthreads();
  }

  // pair-combine: waves 4-7 publish partials; waves 0-3 add + store.
  float* red = (float*)smem;   // scratch; layout: 4 groups x 2048 f32 + lp
  float* lpred = red + 8192;
  if (wave >= 4) {
    float* basep = red + w03 * 2048;
#pragma unroll
    for (int dt = 0; dt < 2; dt++)
#pragma unroll
      for (int r = 0; r < 4; r++) {
        f32x4 c4 = {oacc[dt][4 * r + 0], oacc[dt][4 * r + 1],
                    oacc[dt][4 * r + 2], oacc[dt][4 * r + 3]};
        ((f32x4*)basep)[lane * 8 + ((dt * 4 + r) ^ (lane & 7))] = c4;
      }
    lpred[w03 * 64 + lane] = lacc[0];
  }
  __syncthreads();
  if (wave < 4) {
    float* basep = red + w03 * 2048;
#pragma unroll
    for (int dt = 0; dt < 2; dt++)
#pragma unroll
      for (int r = 0; r < 4; r++) {
        f32x4 c4 = ((f32x4*)basep)[lane * 8 + ((dt * 4 + r) ^ (lane & 7))];
        oacc[dt][4 * r + 0] += c4[0];
        oacc[dt][4 * r + 1] += c4[1];
        oacc[dt][4 * r + 2] += c4[2];
        oacc[dt][4 * r + 3] += c4[3];
      }
    float rl = 1.0f / (lacc[0] + lpred[w03 * 64 + lane]);

    // epilogue: O^T frag col=q=l31, row d = 32*dt + 8*(reg>>2) + 4*hi + (reg&3)
    unsigned short* ob = aout + (size_t)(b * 2048 + q0 + w03 * 32 + l31) * 1024 + h * 64;
#pragma unroll
    for (int dt = 0; dt < 2; dt++)
#pragma unroll
      for (int rq = 0; rq < 4; rq++) {
        union { uint2 u; ushort4 w; } pk;
        pk.u.x = cvt_pk_bf16(oacc[dt][4 * rq + 0] * rl, oacc[dt][4 * rq + 1] * rl);
        pk.u.y = cvt_pk_bf16(oacc[dt][4 * rq + 2] * rl, oacc[dt][4 * rq + 3] * rl);
        *(ushort4*)&ob[dt * 32 + rq * 8 + hi * 4] = pk.w;
      }
  }
}

// ---------------------------------------------------------------------------
extern "C" void kernel_launch(void* const* d_in, const int* in_sizes, int n_in,
                              void* d_out, int out_size, void* d_ws, size_t ws_size,
                              hipStream_t stream) {
  (void)in_sizes; (void)n_in; (void)out_size; (void)ws_size;
  const float* x     = (const float*)d_in[0];
  const float* w_in  = (const float*)d_in[1];
  const float* b_in  = (const float*)d_in[2];
  const float* w_out = (const float*)d_in[3];
  const float* b_out = (const float*)d_in[4];
  char* ws = (char*)d_ws;
  unsigned short* xb    = (unsigned short*)(ws + 0);          //  8 MB
  unsigned short* wint  = (unsigned short*)(ws + 8388608);    //  6 MB
  unsigned short* woutt = (unsigned short*)(ws + 14680064);   //  2 MB
  unsigned short* qkv   = (unsigned short*)(ws + 16777216);   // 24 MB
  unsigned short* vt    = (unsigned short*)(ws + 41943040);   //  8 MB
  unsigned short* attn  = (unsigned short*)(ws + 50331648);   //  8 MB
  float* out = (float*)d_out;

  const float QSCALE = 0.125f * 1.44269504088896f;  // fold 1/sqrt(64) * log2(e)

  prep_kernel<<<5120, 256, 0, stream>>>(x, xb, w_in, wint, w_out, woutt);
  gemm_bt1<<<dim3(24, 32), 256, 0, stream>>>(xb, wint, b_in, qkv, vt,
                                             4096, 3072, 1024, 1024, QSCALE);
  attn_kernel<<<512, 512, 0, stream>>>(qkv, vt, attn);
  gemm_bt2<<<dim3(8, 32), 512, 0, stream>>>(attn, woutt, b_out, out, 4096, 1024, 1024);
}